// Round 3
// baseline (335.295 us; speedup 1.0000x reference)
//
#include <hip/hip_runtime.h>
#include <hip/hip_bf16.h>
#include <cstdint>
#include <cmath>

// Problem constants
#define B_   2
#define S_   2048
#define H_   2048
#define NH_  32
#define NKV_ 8
#define HD_  64

using bf16x8 = __attribute__((ext_vector_type(8))) short;
using f32x4  = __attribute__((ext_vector_type(4))) float;

#define MFMA16(a, b, c) __builtin_amdgcn_mfma_f32_16x16x32_bf16((a), (b), (c), 0, 0, 0)

__device__ __forceinline__ short f2bf(float f) {   // round-nearest-even
  uint32_t u = __float_as_uint(f);
  uint32_t r = (u + 0x7fffu + ((u >> 16) & 1u)) >> 16;
  return (short)r;
}
__device__ __forceinline__ float bf2f(short s) {
  return __uint_as_float(((uint32_t)(uint16_t)s) << 16);
}
// packed 2xf32 -> 2xbf16 (hardware op when available)
__device__ __forceinline__ uint32_t f2bf_pk(float a, float b) {
#if __has_builtin(__builtin_amdgcn_cvt_pk_bf16_f32)
  auto r = __builtin_amdgcn_cvt_pk_bf16_f32(a, b);
  uint32_t u; __builtin_memcpy(&u, &r, sizeof(u));
  return u;
#else
  uint32_t ua = (__float_as_uint(a) + 0x8000u) >> 16;
  uint32_t ub = (__float_as_uint(b) + 0x8000u) >> 16;
  return ua | (ub << 16);
#endif
}
// raw v_exp_f32 (2^x)
__device__ __forceinline__ float fast_exp2(float x) {
#if __has_builtin(__builtin_amdgcn_exp2f)
  return __builtin_amdgcn_exp2f(x);
#else
  return exp2f(x);
#endif
}

__device__ __forceinline__ void gload_lds16(const void* g, void* l) {
  __builtin_amdgcn_global_load_lds((const __attribute__((address_space(1))) void*)g,
                                   (__attribute__((address_space(3))) void*)l, 16, 0, 0);
}

// ---------------- fused fp32 -> bf16 convert for all 5 tensors ------------------
struct Cvt5Args {
  const float *s0, *s1, *s2, *s3, *s4;
  short *d0, *d1, *d2, *d3, *d4;
};
#define CV0 2097152             // hs      (float4 units)
#define CV1 (CV0 + 1048576)     // Wq
#define CV2 (CV1 + 262144)      // Wk
#define CV3 (CV2 + 262144)      // Wv
#define CV4 (CV3 + 1048576)     // Wo -> total 4718592
__global__ void cvt5_kernel(Cvt5Args a) {
  int i = blockIdx.x * blockDim.x + threadIdx.x;
  const float* s; short* d; int off;
  if      (i < CV0) { s = a.s0; d = a.d0; off = i; }
  else if (i < CV1) { s = a.s1; d = a.d1; off = i - CV0; }
  else if (i < CV2) { s = a.s2; d = a.d2; off = i - CV1; }
  else if (i < CV3) { s = a.s3; d = a.d3; off = i - CV2; }
  else              { s = a.s4; d = a.d4; off = i - CV3; }
  const float4 v = ((const float4*)s)[off];
  uint2 o;
  o.x = (uint32_t)(uint16_t)f2bf(v.x) | ((uint32_t)(uint16_t)f2bf(v.y) << 16);
  o.y = (uint32_t)(uint16_t)f2bf(v.z) | ((uint32_t)(uint16_t)f2bf(v.w) << 16);
  ((uint2*)d)[off] = o;
}

// ---------------- GEMM core: C[M,N] = A[M,K] * B[N,K]^T ------------------------
// 128x128 tile, BK=64, double-buffered LDS with COUNTED vmcnt (T4): the next
// K-tile's 8 global_load_lds stay in flight across both raw s_barriers, so the
// load latency hides entirely under compute(t). No vmcnt(0) drain in the loop.
// LDS is XOR-swizzled (T2, both-sides-or-neither, rule 21): linear LDS dest
// (gload_lds requirement) + inverse-swizzled GLOBAL source chunk
// cS = (tid&7)^((tid>>3)&7), and the ds_read applies chunk^(l15&7) -> 2-way
// bank aliasing (free) instead of the 16-way conflict of linear [128][64].
template <bool F32OUT>
__device__ __forceinline__ void gemm_core(
    const short* __restrict__ A, const short* __restrict__ Bm,
    short* __restrict__ Cb, float* __restrict__ Cf,
    const int N, const long tileM, const long tileN, const int K)
{
  __shared__ __align__(16) short As[2][128 * 64];   // 32 KiB
  __shared__ __align__(16) short Bs[2][128 * 64];   // 32 KiB

  const int tid  = threadIdx.x;
  const int lane = tid & 63;
  const int quad = lane >> 4;
  const int l15  = lane & 15;
  const int wave = tid >> 6;
  const int wm   = (wave >> 1) * 64;
  const int wn   = (wave & 1) * 64;
  const int xsw  = l15 & 7;                 // read-side XOR swizzle

  f32x4 acc[4][4];
#pragma unroll
  for (int i = 0; i < 4; ++i)
#pragma unroll
    for (int j = 0; j < 4; ++j) acc[i][j] = f32x4{0.f, 0.f, 0.f, 0.f};

  // Staging: thread c = tid + 256p covers row c>>3, LDS chunk c&7 (lane-linear
  // dest = c*16B). Global source chunk is the swizzle inverse.
  const int cS = (tid & 7) ^ ((tid >> 3) & 7);
  const short* gA[4]; const short* gB[4];
#pragma unroll
  for (int p = 0; p < 4; ++p) {
    const long row = (tid >> 3) + 32 * p;
    gA[p] = A  + (tileM + row) * K + cS * 8;
    gB[p] = Bm + (tileN + row) * K + cS * 8;
  }

  auto stage = [&](int buf, int t) {
    const long ko = (long)t * 64;
    short* la = &As[buf][0];
    short* lb = &Bs[buf][0];
#pragma unroll
    for (int p = 0; p < 4; ++p) {
      gload_lds16(gA[p] + ko, la + (tid + p * 256) * 8);
      gload_lds16(gB[p] + ko, lb + (tid + p * 256) * 8);
    }
  };

  const int NT = K / 64;
  stage(0, 0);

  for (int t = 0; t < NT; ++t) {
    const int cur = t & 1;
    if (t + 1 < NT) {
      stage(cur ^ 1, t + 1);                               // 8 loads -> other buf
      asm volatile("s_waitcnt vmcnt(8)" ::: "memory");     // wait stage(t) only
    } else {
      asm volatile("s_waitcnt vmcnt(0)" ::: "memory");
    }
    asm volatile("s_barrier" ::: "memory");                // buf[cur] ready (all waves)

    const short* Ab = &As[cur][0];
    const short* Bb = &Bs[cur][0];
#pragma unroll
    for (int kk = 0; kk < 2; ++kk) {
      bf16x8 af[4], bfr[4];
#pragma unroll
      for (int i = 0; i < 4; ++i)
        af[i] = *(const bf16x8*)&Ab[(wm + i * 16 + l15) * 64 +
                                    (((kk * 4 + quad) ^ xsw) << 3)];
#pragma unroll
      for (int j = 0; j < 4; ++j)
        bfr[j] = *(const bf16x8*)&Bb[(wn + j * 16 + l15) * 64 +
                                     (((kk * 4 + quad) ^ xsw) << 3)];
#pragma unroll
      for (int i = 0; i < 4; ++i)
#pragma unroll
        for (int j = 0; j < 4; ++j)
          acc[i][j] = MFMA16(af[i], bfr[j], acc[i][j]);
    }

    asm volatile("s_waitcnt lgkmcnt(0)" ::: "memory");     // reads serviced
    asm volatile("s_barrier" ::: "memory");                // release buf[cur^1]
  }

#pragma unroll
  for (int i = 0; i < 4; ++i)
#pragma unroll
    for (int j = 0; j < 4; ++j)
#pragma unroll
      for (int r = 0; r < 4; ++r) {
        long row = tileM + wm + i * 16 + quad * 4 + r;
        long col = tileN + wn + j * 16 + l15;
        float v = acc[i][j][r];
        if constexpr (F32OUT) Cf[row * N + col] = v;
        else                  Cb[row * N + col] = f2bf(v);
      }
}

// Fused Q,K,V projection: one launch, grid (24, 32) = 768 blocks (3/CU).
// x 0..15 -> Q (N=2048), 16..19 -> K (N=512), 20..23 -> V (N=512).
__global__ __launch_bounds__(256) void gemm_qkv(
    const short* __restrict__ A,
    const short* __restrict__ Bq, const short* __restrict__ Bk,
    const short* __restrict__ Bv,
    short* __restrict__ Cq, short* __restrict__ Ck, short* __restrict__ Cv)
{
  const int x = blockIdx.x;
  const short* Bm; short* Cb; int N; long tileN;
  if (x < 16)      { Bm = Bq; Cb = Cq; N = 2048; tileN = (long)x * 128; }
  else if (x < 20) { Bm = Bk; Cb = Ck; N = 512;  tileN = (long)(x - 16) * 128; }
  else             { Bm = Bv; Cb = Cv; N = 512;  tileN = (long)(x - 20) * 128; }
  gemm_core<false>(A, Bm, Cb, nullptr, N, (long)blockIdx.y * 128, tileN, 2048);
}

// Output projection with fp32 epilogue
__global__ __launch_bounds__(256) void gemm_out(
    const short* __restrict__ A, const short* __restrict__ Bm,
    float* __restrict__ Cf)
{
  gemm_core<true>(A, Bm, nullptr, Cf, 2048,
                  (long)blockIdx.y * 128, (long)blockIdx.x * 128, 2048);
}

// ---------------- fused RoPE (Q,K in-place) + V transpose (slot-permuted) -------
// Q scaled by (1/8)*log2(e) so attention can use exp2 directly.
// Trig via native v_sin/v_cos after revolution-space fract reduction: phase
// error ~1.2e-4 rad, same order as the reference's own f32 rounding of s*inv.
// V^T is written with each 32-key group PERMUTED into MFMA B-slot order:
//   slot(key) = (key&32) | ((key>>2)&3)*8 | ((key>>4)&1)*4 | (key&3)
// so the attention PV^T A-fragment is a contiguous 16B ds_read_b128.
#define ROPE_BLOCKS 20480
__global__ void rope_vtrans_kernel(short* __restrict__ Q, short* __restrict__ Kp,
                                   const short* __restrict__ Vm, short* __restrict__ Vt) {
  __shared__ short tile[64][65];
  if (blockIdx.x < ROPE_BLOCKS) {
    const int QP = (B_ * S_) * NH_ * (HD_ / 2);  // 4,194,304
    int t = blockIdx.x * blockDim.x + threadIdx.x;
    short* ptr; long base; int i, s; float scale;
    if (t < QP) {
      int row = t >> 10, rem = t & 1023, head = rem >> 5; i = rem & 31;
      ptr = Q; base = (long)row * (NH_ * HD_) + head * HD_; s = row & (S_ - 1);
      scale = 0.125f * 1.44269504f;
    } else {
      int t2 = t - QP;
      int row = t2 >> 8, rem = t2 & 255, head = rem >> 5; i = rem & 31;
      ptr = Kp; base = (long)row * (NKV_ * HD_) + head * HD_; s = row & (S_ - 1);
      scale = 1.0f;
    }
    // inv_freq/2pi = 10000^(-i/32) / (2*pi); phase = 2*pi*fract(s*invr)
    float invr = exp2f((float)i * -0.41524101f) * 0.15915494309f;
    float rev = (float)s * invr;
    rev -= floorf(rev);                       // [0,1)
    float ar = rev * 6.28318530718f;          // [0,2pi) -- native-range safe
    float c = __cosf(ar), sn = __sinf(ar);
    float x0 = bf2f(ptr[base + i]);
    float x1 = bf2f(ptr[base + i + 32]);
    ptr[base + i]      = f2bf((x0 * c - x1 * sn) * scale);
    ptr[base + i + 32] = f2bf((x1 * c + x0 * sn) * scale);
  } else {
    int blk = blockIdx.x - ROPE_BLOCKS;
    int s0 = (blk & 31) * 64;
    int h  = (blk >> 5) & 7;
    int b  = blk >> 8;
    int tid = threadIdx.x;
#pragma unroll
    for (int it = 0; it < 16; ++it) {
      int idx = tid + it * 256;
      int r = idx >> 6, c = idx & 63;
      tile[r][c] = Vm[((long)(b * S_ + s0 + r)) * (NKV_ * HD_) + h * HD_ + c];
    }
    __syncthreads();
#pragma unroll
    for (int it = 0; it < 16; ++it) {
      int idx = tid + it * 256;
      int d = idx >> 6, s = idx & 63;
      int slot = (s & 0x20) | (((s >> 2) & 3) << 3) | (((s >> 4) & 1) << 2) | (s & 3);
      Vt[((long)((b * NKV_ + h) * HD_ + d)) * S_ + s0 + slot] = tile[s][d];
    }
  }
}

// ---------------- Flash attention (causal, GQA), transposed-score form ----------
// 128 q-rows per block (two 16-row fragments per wave: rows w*16+l15 and +64),
// so every K/V ds_read, staging DMA, barrier and vmcnt wait is amortized over
// 2x the MFMA work. Grid (16, 64) = 1024 blocks, qt = 15 - blockIdx.x (LPT).
// 3-buffer, 2-deep prefetch with COUNTED vmcnt(4) (T4): stage(kb+2) issued
// right after the single per-iteration barrier; no vmcnt(0) drain except the
// final iteration. Safety (one barrier/iter): writer DMA into buf[j] at iter
// kb is issued AFTER barrier(kb); all waves' reads of buf[j] (iter kb-1)
// completed at their lgkmcnt(0) BEFORE entering barrier(kb). Reader safety:
// each wave's vmcnt(4) confirms its own stage(kb) loads; the barrier makes
// that collective before any ds_read of buf[kb%3].
// Causal handling (interleaved halves, uniform across waves):
//   frag1 (rows +64): diagonal mask only at kb==kmax.
//   frag0: diagonal mask at kb==kmax-1; fully masked at kb==kmax -> skipped.
// No-max softmax: scores pre-scaled into log2 domain, exp2 cannot overflow.
__global__ __launch_bounds__(256, 3) void attn_kernel(
    const short* __restrict__ Q, const short* __restrict__ Km,
    const short* __restrict__ Vt, short* __restrict__ O)
{
  const int qt = 15 - (int)blockIdx.x;   // 128-row q-tile, long blocks first
  const int kmax = 2 * qt + 1;           // last 64-key tile index
  const int bh = blockIdx.y;
  const int b = bh >> 5, h = bh & 31, hkv = h >> 2;
  const int tid = threadIdx.x, lane = tid & 63, w = tid >> 6;
  const int quad = lane >> 4, l15 = lane & 15;

  __shared__ __align__(16) short Ks[3][64 * 64];   // [key][feature], chunk-swizzled
  __shared__ __align__(16) short Vs[3][64 * 64];   // [d][slot], chunk-swizzled

  const int qbase = qt * 128 + w * 16;   // frag0 rows qbase+l15, frag1 +64
  const short* qb0 = Q + ((long)(b * S_ + qbase + l15)) * (NH_ * HD_) + h * HD_;
  const short* qb1 = qb0 + 64L * (NH_ * HD_);
  const bf16x8 aq00 = *(const bf16x8*)(qb0 + quad * 8);
  const bf16x8 aq01 = *(const bf16x8*)(qb0 + 32 + quad * 8);
  const bf16x8 aq10 = *(const bf16x8*)(qb1 + quad * 8);
  const bf16x8 aq11 = *(const bf16x8*)(qb1 + 32 + quad * 8);

  f32x4 o0[4], o1[4];
#pragma unroll
  for (int i = 0; i < 4; ++i) {
    o0[i] = f32x4{0.f, 0.f, 0.f, 0.f};
    o1[i] = f32x4{0.f, 0.f, 0.f, 0.f};
  }
  f32x4 li0 = f32x4{0.f, 0.f, 0.f, 0.f};
  f32x4 li1 = f32x4{0.f, 0.f, 0.f, 0.f};

  const short* kg = Km + ((long)(b * S_)) * (NKV_ * HD_) + hkv * HD_;
  const short* vg = Vt + ((long)((b * NKV_ + hkv) * HD_)) * S_;

  // Precomputed staging addresses (lane-constant; k-loop adds a linear offset).
  const int rK = tid >> 3;                       // 0..31 (second half adds 32)
  const int cC = (tid & 7) ^ (rK & 7);           // +32 preserves &7
  const short* kSrc = kg + (long)rK * (NKV_ * HD_) + cC * 8;
  const short* vSrc = vg + (long)rK * S_ + cC * 8;
  short* kDst = &Ks[0][tid * 8];
  short* vDst = &Vs[0][tid * 8];

  auto stage = [&](int buf, int kb) {
    const long ko = (long)kb * 64 * (NKV_ * HD_);
    const long vo = (long)kb * 64;
    const int bo = buf * 4096;
    gload_lds16(kSrc + ko,                      kDst + bo);
    gload_lds16(kSrc + ko + 32L * (NKV_ * HD_), kDst + bo + 2048);
    gload_lds16(vSrc + vo,                      vDst + bo);
    gload_lds16(vSrc + vo + 32L * S_,           vDst + bo + 2048);
  };

  stage(0, 0);
  if (kmax >= 1) stage(1, 1);

  const int thr = w * 16 + l15;   // diagonal mask threshold (key offset vs row)
  union U8 { uint32_t u[4]; bf16x8 v; };

  int cur = 0;
  for (int kb = 0; kb <= kmax; ++kb) {
    if (kb < kmax) asm volatile("s_waitcnt vmcnt(4)" ::: "memory");
    else           asm volatile("s_waitcnt vmcnt(0)" ::: "memory");
    asm volatile("s_barrier" ::: "memory");      // buf[cur] staged, prev reads done
    if (kb + 2 <= kmax) {
      int nb = cur + 2; if (nb >= 3) nb -= 3;
      stage(nb, kb + 2);                         // 2-deep prefetch
    }
    const short* Kb = &Ks[cur][0];
    const short* Vb = &Vs[cur][0];
    const bool doF0 = (kb != kmax);              // frag0 fully masked at kmax

    // ---- Sc^T = K·Q^T (K-frags shared across both q-fragments) ----
    f32x4 s0[4], s1[4];
    __builtin_amdgcn_s_setprio(1);
#pragma unroll
    for (int nt = 0; nt < 4; ++nt) {
      const int r = nt * 16 + l15;
      bf16x8 k0 = *(const bf16x8*)&Kb[(r * 8 + ((quad)     ^ (r & 7))) * 8];
      bf16x8 k1 = *(const bf16x8*)&Kb[(r * 8 + ((quad + 4) ^ (r & 7))) * 8];
      f32x4 t = f32x4{0.f, 0.f, 0.f, 0.f};
      t = MFMA16(k0, aq10, t);
      t = MFMA16(k1, aq11, t);
      s1[nt] = t;
      if (doF0) {
        f32x4 u = f32x4{0.f, 0.f, 0.f, 0.f};
        u = MFMA16(k0, aq00, u);
        u = MFMA16(k1, aq01, u);
        s0[nt] = u;
      }
    }
    __builtin_amdgcn_s_setprio(0);

    // ---- causal mask (diagonal tiles only) ----
    if (kb == kmax) {            // frag1 diagonal
#pragma unroll
      for (int nt = 0; nt < 4; ++nt) {
        const int base = nt * 16 + quad * 4;
#pragma unroll
        for (int rr = 0; rr < 4; ++rr)
          if (base + rr > thr) s1[nt][rr] = -1e30f;
      }
    }
    if (doF0 && kb == kmax - 1) {   // frag0 diagonal
#pragma unroll
      for (int nt = 0; nt < 4; ++nt) {
        const int base = nt * 16 + quad * 4;
#pragma unroll
        for (int rr = 0; rr < 4; ++rr)
          if (base + rr > thr) s0[nt][rr] = -1e30f;
      }
    }

    // ---- exp2 + pack to P^T B-fragments (registers only) ----
    U8 p0[2], p1[2];
#pragma unroll
    for (int kt = 0; kt < 2; ++kt) {
      float e0 = fast_exp2(s1[2 * kt][0]),     e1 = fast_exp2(s1[2 * kt][1]);
      float e2 = fast_exp2(s1[2 * kt][2]),     e3 = fast_exp2(s1[2 * kt][3]);
      float e4 = fast_exp2(s1[2 * kt + 1][0]), e5 = fast_exp2(s1[2 * kt + 1][1]);
      float e6 = fast_exp2(s1[2 * kt + 1][2]), e7 = fast_exp2(s1[2 * kt + 1][3]);
      p1[kt].u[0] = f2bf_pk(e0, e1);
      p1[kt].u[1] = f2bf_pk(e2, e3);
      p1[kt].u[2] = f2bf_pk(e4, e5);
      p1[kt].u[3] = f2bf_pk(e6, e7);
      li1 += f32x4{e0, e1, e2, e3};
      li1 += f32x4{e4, e5, e6, e7};
    }
    if (doF0) {
#pragma unroll
      for (int kt = 0; kt < 2; ++kt) {
        float e0 = fast_exp2(s0[2 * kt][0]),     e1 = fast_exp2(s0[2 * kt][1]);
        float e2 = fast_exp2(s0[2 * kt][2]),     e3 = fast_exp2(s0[2 * kt][3]);
        float e4 = fast_exp2(s0[2 * kt + 1][0]), e5 = fast_exp2(s0[2 * kt + 1][1]);
        float e6 = fast_exp2(s0[2 * kt + 1][2]), e7 = fast_exp2(s0[2 * kt + 1][3]);
        p0[kt].u[0] = f2bf_pk(e0, e1);
        p0[kt].u[1] = f2bf_pk(e2, e3);
        p0[kt].u[2] = f2bf_pk(e4, e5);
        p0[kt].u[3] = f2bf_pk(e6, e7);
        li0 += f32x4{e0, e1, e2, e3};
        li0 += f32x4{e4, e5, e6, e7};
      }
    }

    // ---- O^T += V^T · P^T (V A-frags shared across both q-fragments) ----
    __builtin_amdgcn_s_setprio(1);
#pragma unroll
    for (int kt = 0; kt < 2; ++kt) {
      bf16x8 vf[4];
#pragma unroll
      for (int dt = 0; dt < 4; ++dt)
        vf[dt] = *(const bf16x8*)&Vb[(dt * 16 + l15) * 64 +
                                     (((kt * 4 + quad) ^ (l15 & 7)) << 3)];
#pragma unroll
      for (int dt = 0; dt < 4; ++dt)
        o1[dt] = MFMA16(vf[dt], p1[kt].v, o1[dt]);
      if (doF0) {
#pragma unroll
        for (int dt = 0; dt < 4; ++dt)
          o0[dt] = MFMA16(vf[dt], p0[kt].v, o0[dt]);
      }
    }
    __builtin_amdgcn_s_setprio(0);

    asm volatile("s_waitcnt lgkmcnt(0)" ::: "memory");   // all LDS reads serviced
    ++cur; if (cur == 3) cur = 0;
  }

  // ---- epilogue: O^T C-layout -> lane holds qrow=l15, d = dt*16+quad*4+r ----
  auto epi = [&](f32x4 (&o)[4], const f32x4& li4, int qrow0) {
    float l = (li4[0] + li4[1]) + (li4[2] + li4[3]);
    l += __shfl_xor(l, 16, 64);
    l += __shfl_xor(l, 32, 64);
    float invl = 1.0f / l;
    long orow = (long)(b * S_ + qrow0 + l15);
#pragma unroll
    for (int dt = 0; dt < 4; ++dt) {
      uint2 st;
      st.x = f2bf_pk(o[dt][0] * invl, o[dt][1] * invl);
      st.y = f2bf_pk(o[dt][2] * invl, o[dt][3] * invl);
      *(uint2*)&O[orow * (NH_ * HD_) + h * HD_ + dt * 16 + quad * 4] = st;
    }
  };
  epi(o1, li1, qbase + 64);
  epi(o0, li0, qbase);
}

// ---------------- launch -------------------------------------------------------
extern "C" void kernel_launch(void* const* d_in, const int* in_sizes, int n_in,
                              void* d_out, int out_size, void* d_ws, size_t ws_size,
                              hipStream_t stream) {
  const float* hs = (const float*)d_in[0];
  const float* Wq = (const float*)d_in[1];
  const float* Wk = (const float*)d_in[2];
  const float* Wv = (const float*)d_in[3];
  const float* Wo = (const float*)d_in[4];
  float* out = (float*)d_out;

  char* p = (char*)d_ws;
  auto carve = [&](size_t elems) { short* r = (short*)p; p += elems * 2; return r; };
  short* Xb  = carve(8388608);   // hidden bf16 [4096,2048]
  short* Wqb = carve(4194304);
  short* Wkb = carve(1048576);
  short* Wvb = carve(1048576);
  short* Wob = carve(4194304);
  short* Qm  = carve(8388608);   // Q [4096,2048]
  short* Kmt = carve(2097152);   // K [4096,512]
  short* Vmt = carve(2097152);   // V [4096,512]
  short* Vtt = carve(2097152);   // V^T [B,KV,HD,S] (slot-permuted)
  short* Om  = carve(8388608);   // attn out [4096,2048]

  Cvt5Args ca{hs, Wq, Wk, Wv, Wo, Xb, Wqb, Wkb, Wvb, Wob};
  cvt5_kernel<<<CV4 / 256, 256, 0, stream>>>(ca);

  // Fused Q+K+V projections: [4096,2048] x {Wq,Wk,Wv}^T in one launch
  gemm_qkv<<<dim3(24, 32), 256, 0, stream>>>(Xb, Wqb, Wkb, Wvb, Qm, Kmt, Vmt);

  rope_vtrans_kernel<<<ROPE_BLOCKS + 512, 256, 0, stream>>>(Qm, Kmt, Vmt, Vtt);
  attn_kernel<<<dim3(16, 64, 1), 256, 0, stream>>>(Qm, Kmt, Vtt, Om);

  // Output projection with fp32 epilogue into d_out
  gemm_out<<<dim3(16, 32), 256, 0, stream>>>(Om, Wob, out);
}

// Round 5
// 332.389 us; speedup vs baseline: 1.0087x; 1.0087x over previous
//
#include <hip/hip_runtime.h>
#include <hip/hip_bf16.h>
#include <cstdint>
#include <cmath>

// Problem constants
#define B_   2
#define S_   2048
#define H_   2048
#define NH_  32
#define NKV_ 8
#define HD_  64

using bf16x8 = __attribute__((ext_vector_type(8))) short;
using f32x4  = __attribute__((ext_vector_type(4))) float;

#define MFMA16(a, b, c) __builtin_amdgcn_mfma_f32_16x16x32_bf16((a), (b), (c), 0, 0, 0)

__device__ __forceinline__ short f2bf(float f) {   // round-nearest-even
  uint32_t u = __float_as_uint(f);
  uint32_t r = (u + 0x7fffu + ((u >> 16) & 1u)) >> 16;
  return (short)r;
}
__device__ __forceinline__ float bf2f(short s) {
  return __uint_as_float(((uint32_t)(uint16_t)s) << 16);
}
// packed 2xf32 -> 2xbf16 (hardware op when available)
__device__ __forceinline__ uint32_t f2bf_pk(float a, float b) {
#if __has_builtin(__builtin_amdgcn_cvt_pk_bf16_f32)
  auto r = __builtin_amdgcn_cvt_pk_bf16_f32(a, b);
  uint32_t u; __builtin_memcpy(&u, &r, sizeof(u));
  return u;
#else
  uint32_t ua = (__float_as_uint(a) + 0x8000u) >> 16;
  uint32_t ub = (__float_as_uint(b) + 0x8000u) >> 16;
  return ua | (ub << 16);
#endif
}
// raw v_exp_f32 (2^x)
__device__ __forceinline__ float fast_exp2(float x) {
#if __has_builtin(__builtin_amdgcn_exp2f)
  return __builtin_amdgcn_exp2f(x);
#else
  return exp2f(x);
#endif
}

__device__ __forceinline__ void gload_lds16(const void* g, void* l) {
  __builtin_amdgcn_global_load_lds((const __attribute__((address_space(1))) void*)g,
                                   (__attribute__((address_space(3))) void*)l, 16, 0, 0);
}

// ---------------- fused fp32 -> bf16 convert for all 5 tensors ------------------
struct Cvt5Args {
  const float *s0, *s1, *s2, *s3, *s4;
  short *d0, *d1, *d2, *d3, *d4;
};
#define CV0 2097152             // hs      (float4 units)
#define CV1 (CV0 + 1048576)     // Wq
#define CV2 (CV1 + 262144)      // Wk
#define CV3 (CV2 + 262144)      // Wv
#define CV4 (CV3 + 1048576)     // Wo -> total 4718592
__global__ void cvt5_kernel(Cvt5Args a) {
  int i = blockIdx.x * blockDim.x + threadIdx.x;
  const float* s; short* d; int off;
  if      (i < CV0) { s = a.s0; d = a.d0; off = i; }
  else if (i < CV1) { s = a.s1; d = a.d1; off = i - CV0; }
  else if (i < CV2) { s = a.s2; d = a.d2; off = i - CV1; }
  else if (i < CV3) { s = a.s3; d = a.d3; off = i - CV2; }
  else              { s = a.s4; d = a.d4; off = i - CV3; }
  const float4 v = ((const float4*)s)[off];
  uint2 o;
  o.x = (uint32_t)(uint16_t)f2bf(v.x) | ((uint32_t)(uint16_t)f2bf(v.y) << 16);
  o.y = (uint32_t)(uint16_t)f2bf(v.z) | ((uint32_t)(uint16_t)f2bf(v.w) << 16);
  ((uint2*)d)[off] = o;
}

// ---------------- 256x256 8-wave GEMM (QKV projection) -------------------------
// C[M,N] = A[M,K]*B[N,K]^T, BM=BN=256, BK=64, 512 threads = 8 waves (2M x 4N).
// Per wave: 128x64 output = 8x4 16x16 frags (acc = 128 VGPR).
// LDS: 2 dbuf x (A 256x64 + B 256x64) bf16 = 128 KiB; 1 block/CU, 2 waves/SIMD.
// Protocol (inherited from the verified 128-tile kernel): at phase 0 of tile t,
// issue ALL 8 gload_lds for tile t+1 into slot (t+1)&1; compute 4 quadrant
// phases of tile t from slot t&1; at end of phase 3, vmcnt(0) (loads are ~3
// phases old -> near-free) + lgkmcnt(0) (this wave's reads of slot t&1 done)
// + s_barrier => slot t&1 free for writing and slot (t+1)&1 globally staged.
// Inner phase barriers only align wave schedules (no data hazard: DMA writes
// the other slot). XOR swizzle identical to the verified 128-tile kernel:
// linear LDS dest + inverse-swizzled global source chunk, read-side
// chunk ^ (row&7) -> 2-way bank aliasing (free).
// Quadrant phases (qi = mf-half, qj = nf-half): p0 (0,0) reads A0(8)+Bn0(4);
// p1 (0,1) reads Bn1(4), reuses A0; p2 (1,1) reads A1(8), reuses Bn1;
// p3 (1,0) re-reads Bn0(4), reuses A1. K-order per acc: tiles outer, kk inner
// -> bit-identical accumulation to the 128-tile version.
__global__ __launch_bounds__(512, 2) void gemm_qkv256(
    const short* __restrict__ A,
    const short* __restrict__ Bq, const short* __restrict__ Bk,
    const short* __restrict__ Bv,
    short* __restrict__ Cq, short* __restrict__ Ck, short* __restrict__ Cv)
{
  __shared__ __align__(16) short As[2][256 * 64];   // 64 KiB
  __shared__ __align__(16) short Bs[2][256 * 64];   // 64 KiB

  const int x = blockIdx.x;
  const short* Bm; short* Cb; int N; long tileN;
  if (x < 8)       { Bm = Bq; Cb = Cq; N = 2048; tileN = (long)x * 256; }
  else if (x < 10) { Bm = Bk; Cb = Ck; N = 512;  tileN = (long)(x - 8) * 256; }
  else             { Bm = Bv; Cb = Cv; N = 512;  tileN = (long)(x - 10) * 256; }
  const long tileM = (long)blockIdx.y * 256;
  const int  K = 2048;

  const int tid  = threadIdx.x;
  const int lane = tid & 63;
  const int quad = lane >> 4;
  const int l15  = lane & 15;
  const int wave = tid >> 6;
  const int wm   = (wave >> 2) * 128;     // 0 / 128
  const int wn   = (wave & 3) * 64;       // 0..192
  const int xsw  = l15 & 7;               // read-side XOR swizzle (row&7 == l15&7)

  f32x4 acc[8][4];
#pragma unroll
  for (int i = 0; i < 8; ++i)
#pragma unroll
    for (int j = 0; j < 4; ++j) acc[i][j] = f32x4{0.f, 0.f, 0.f, 0.f};

  // Staging: thread c = tid + 512p covers row c>>3 (0..255), LDS chunk c&7
  // (lane-linear dest = c*16B). Global source chunk is the swizzle inverse.
  const int cS = (tid & 7) ^ ((tid >> 3) & 7);
  const short* gA[4]; const short* gB[4];
#pragma unroll
  for (int p = 0; p < 4; ++p) {
    const long row = (tid >> 3) + 64 * p;
    gA[p] = A  + (tileM + row) * K + cS * 8;
    gB[p] = Bm + (tileN + row) * K + cS * 8;
  }

  auto stage = [&](int buf, int t) {
    const long ko = (long)t * 64;
    short* la = &As[buf][0];
    short* lb = &Bs[buf][0];
#pragma unroll
    for (int p = 0; p < 4; ++p) {
      gload_lds16(gA[p] + ko, la + (tid + p * 512) * 8);
      gload_lds16(gB[p] + ko, lb + (tid + p * 512) * 8);
    }
  };

  const int NT = K / 64;                       // 32
  stage(0, 0);
  asm volatile("s_waitcnt vmcnt(0)" ::: "memory");
  asm volatile("s_barrier" ::: "memory");

  bf16x8 af[4][2], bfr[2][2];

  auto ldA = [&](const short* Ab, int qi) {
#pragma unroll
    for (int m = 0; m < 4; ++m) {
      const int r = wm + (qi * 4 + m) * 16 + l15;
#pragma unroll
      for (int kk = 0; kk < 2; ++kk)
        af[m][kk] = *(const bf16x8*)&Ab[r * 64 + (((kk * 4 + quad) ^ xsw) << 3)];
    }
  };
  auto ldB = [&](const short* Bb, int qj) {
#pragma unroll
    for (int n = 0; n < 2; ++n) {
      const int r = wn + (qj * 2 + n) * 16 + l15;
#pragma unroll
      for (int kk = 0; kk < 2; ++kk)
        bfr[n][kk] = *(const bf16x8*)&Bb[r * 64 + (((kk * 4 + quad) ^ xsw) << 3)];
    }
  };
  auto mma = [&](int qi, int qj) {
    __builtin_amdgcn_s_setprio(1);
#pragma unroll
    for (int m = 0; m < 4; ++m)
#pragma unroll
      for (int n = 0; n < 2; ++n)
#pragma unroll
        for (int kk = 0; kk < 2; ++kk)
          acc[qi * 4 + m][qj * 2 + n] =
              MFMA16(af[m][kk], bfr[n][kk], acc[qi * 4 + m][qj * 2 + n]);
    __builtin_amdgcn_s_setprio(0);
  };

  for (int t = 0; t < NT; ++t) {
    const int cur = t & 1;
    const short* Ab = &As[cur][0];
    const short* Bb = &Bs[cur][0];

    // phase 0: stage next tile, quadrant (0,0)
    if (t + 1 < NT) stage(cur ^ 1, t + 1);
    ldA(Ab, 0); ldB(Bb, 0); mma(0, 0);
    asm volatile("s_barrier" ::: "memory");
    // phase 1: quadrant (0,1)
    ldB(Bb, 1); mma(0, 1);
    asm volatile("s_barrier" ::: "memory");
    // phase 2: quadrant (1,1)
    ldA(Ab, 1); mma(1, 1);
    asm volatile("s_barrier" ::: "memory");
    // phase 3: quadrant (1,0)
    ldB(Bb, 0); mma(1, 0);
    asm volatile("s_waitcnt vmcnt(0)" ::: "memory");    // next-tile DMA landed (old)
    asm volatile("s_waitcnt lgkmcnt(0)" ::: "memory");  // my reads of slot cur done
    asm volatile("s_barrier" ::: "memory");             // release slot cur
  }

#pragma unroll
  for (int i = 0; i < 8; ++i)
#pragma unroll
    for (int j = 0; j < 4; ++j)
#pragma unroll
      for (int r = 0; r < 4; ++r) {
        long row = tileM + wm + i * 16 + quad * 4 + r;
        long col = tileN + wn + j * 16 + l15;
        Cb[row * N + col] = f2bf(acc[i][j][r]);
      }
}

// ---------------- 128x128 GEMM (output projection, fp32 epilogue) --------------
// Verified 2-phase counted-vmcnt structure (unchanged from previous round).
__global__ __launch_bounds__(256) void gemm_out(
    const short* __restrict__ A, const short* __restrict__ Bm,
    float* __restrict__ Cf)
{
  __shared__ __align__(16) short As[2][128 * 64];
  __shared__ __align__(16) short Bs[2][128 * 64];

  const int N = 2048, K = 2048;
  const long tileM = (long)blockIdx.y * 128;
  const long tileN = (long)blockIdx.x * 128;

  const int tid  = threadIdx.x;
  const int lane = tid & 63;
  const int quad = lane >> 4;
  const int l15  = lane & 15;
  const int wave = tid >> 6;
  const int wm   = (wave >> 1) * 64;
  const int wn   = (wave & 1) * 64;
  const int xsw  = l15 & 7;

  f32x4 acc[4][4];
#pragma unroll
  for (int i = 0; i < 4; ++i)
#pragma unroll
    for (int j = 0; j < 4; ++j) acc[i][j] = f32x4{0.f, 0.f, 0.f, 0.f};

  const int cS = (tid & 7) ^ ((tid >> 3) & 7);
  const short* gA[4]; const short* gB[4];
#pragma unroll
  for (int p = 0; p < 4; ++p) {
    const long row = (tid >> 3) + 32 * p;
    gA[p] = A  + (tileM + row) * K + cS * 8;
    gB[p] = Bm + (tileN + row) * K + cS * 8;
  }

  auto stage = [&](int buf, int t) {
    const long ko = (long)t * 64;
    short* la = &As[buf][0];
    short* lb = &Bs[buf][0];
#pragma unroll
    for (int p = 0; p < 4; ++p) {
      gload_lds16(gA[p] + ko, la + (tid + p * 256) * 8);
      gload_lds16(gB[p] + ko, lb + (tid + p * 256) * 8);
    }
  };

  const int NT = K / 64;
  stage(0, 0);

  for (int t = 0; t < NT; ++t) {
    const int cur = t & 1;
    if (t + 1 < NT) {
      stage(cur ^ 1, t + 1);
      asm volatile("s_waitcnt vmcnt(8)" ::: "memory");
    } else {
      asm volatile("s_waitcnt vmcnt(0)" ::: "memory");
    }
    asm volatile("s_barrier" ::: "memory");

    const short* Ab = &As[cur][0];
    const short* Bb = &Bs[cur][0];
#pragma unroll
    for (int kk = 0; kk < 2; ++kk) {
      bf16x8 af[4], bfr[4];
#pragma unroll
      for (int i = 0; i < 4; ++i)
        af[i] = *(const bf16x8*)&Ab[(wm + i * 16 + l15) * 64 +
                                    (((kk * 4 + quad) ^ xsw) << 3)];
#pragma unroll
      for (int j = 0; j < 4; ++j)
        bfr[j] = *(const bf16x8*)&Bb[(wn + j * 16 + l15) * 64 +
                                     (((kk * 4 + quad) ^ xsw) << 3)];
#pragma unroll
      for (int i = 0; i < 4; ++i)
#pragma unroll
        for (int j = 0; j < 4; ++j)
          acc[i][j] = MFMA16(af[i], bfr[j], acc[i][j]);
    }

    asm volatile("s_waitcnt lgkmcnt(0)" ::: "memory");
    asm volatile("s_barrier" ::: "memory");
  }

#pragma unroll
  for (int i = 0; i < 4; ++i)
#pragma unroll
    for (int j = 0; j < 4; ++j)
#pragma unroll
      for (int r = 0; r < 4; ++r) {
        long row = tileM + wm + i * 16 + quad * 4 + r;
        long col = tileN + wn + j * 16 + l15;
        Cf[row * N + col] = acc[i][j][r];
      }
}

// ---------------- fused RoPE (Q,K in-place) + V transpose (slot-permuted) -------
// Vectorized x8 (guideline 13): each thread handles 8 consecutive rotation
// pairs via two bf16x8 loads/stores. Per-element math identical to the scalar
// version (same formula, same op order) -> bit-identical output.
// Q scaled by (1/8)*log2(e) so attention can use exp2 directly.
// V^T written with each 32-key group PERMUTED into MFMA B-slot order.
#define ROPE_BLOCKS 2560          // Q: 2048 blocks, K: 512 blocks (x8 vectorized)
__global__ void rope_vtrans_kernel(short* __restrict__ Q, short* __restrict__ Kp,
                                   const short* __restrict__ Vm, short* __restrict__ Vt) {
  __shared__ short tile[64][65];
  if (blockIdx.x < ROPE_BLOCKS) {
    const int QT = (B_ * S_) * NH_ * 4;  // 524288 Q threads (4 groups of 8 per head)
    int t = blockIdx.x * blockDim.x + threadIdx.x;
    short* ptr; long base; int g; float scale;
    int row;
    if (t < QT) {
      row = t >> 7; int rem = t & 127, head = rem >> 2; g = rem & 3;
      ptr = Q; base = (long)row * (NH_ * HD_) + head * HD_;
      scale = 0.125f * 1.44269504f;
    } else {
      int t2 = t - QT;
      row = t2 >> 5; int rem = t2 & 31, head = rem >> 2; g = rem & 3;
      ptr = Kp; base = (long)row * (NKV_ * HD_) + head * HD_;
      scale = 1.0f;
    }
    const int s = row & (S_ - 1);
    const int i0 = g * 8;
    union V8 { bf16x8 v; short e[8]; };
    V8 x0, x1, y0, y1;
    x0.v = *(const bf16x8*)&ptr[base + i0];
    x1.v = *(const bf16x8*)&ptr[base + i0 + 32];
#pragma unroll
    for (int j = 0; j < 8; ++j) {
      const int i = i0 + j;
      float invr = exp2f((float)i * -0.41524101f) * 0.15915494309f;
      float rev = (float)s * invr;
      rev -= floorf(rev);
      float ar = rev * 6.28318530718f;
      float c = __cosf(ar), sn = __sinf(ar);
      float a = bf2f(x0.e[j]);
      float b = bf2f(x1.e[j]);
      y0.e[j] = f2bf((a * c - b * sn) * scale);
      y1.e[j] = f2bf((b * c + a * sn) * scale);
    }
    *(bf16x8*)&ptr[base + i0]      = y0.v;
    *(bf16x8*)&ptr[base + i0 + 32] = y1.v;
  } else {
    int blk = blockIdx.x - ROPE_BLOCKS;
    int s0 = (blk & 31) * 64;
    int h  = (blk >> 5) & 7;
    int b  = blk >> 8;
    int tid = threadIdx.x;
#pragma unroll
    for (int it = 0; it < 16; ++it) {
      int idx = tid + it * 256;
      int r = idx >> 6, c = idx & 63;
      tile[r][c] = Vm[((long)(b * S_ + s0 + r)) * (NKV_ * HD_) + h * HD_ + c];
    }
    __syncthreads();
#pragma unroll
    for (int it = 0; it < 16; ++it) {
      int idx = tid + it * 256;
      int d = idx >> 6, s = idx & 63;
      int slot = (s & 0x20) | (((s >> 2) & 3) << 3) | (((s >> 4) & 1) << 2) | (s & 3);
      Vt[((long)((b * NKV_ + h) * HD_ + d)) * S_ + s0 + slot] = tile[s][d];
    }
  }
}

// ---------------- Flash attention (causal, GQA), transposed-score form ----------
// 128 q-rows per block (two 16-row fragments per wave). Grid (16, 32) x2
// launches (bh halves) so rocprof top-5 shows the other kernels too.
// 3-buffer, 2-deep prefetch with counted vmcnt(4); one barrier per iteration.
__global__ __launch_bounds__(256, 3) void attn_kernel(
    const short* __restrict__ Q, const short* __restrict__ Km,
    const short* __restrict__ Vt, short* __restrict__ O, int bh0)
{
  const int qt = 15 - (int)blockIdx.x;   // 128-row q-tile, long blocks first
  const int kmax = 2 * qt + 1;           // last 64-key tile index
  const int bh = blockIdx.y + bh0;
  const int b = bh >> 5, h = bh & 31, hkv = h >> 2;
  const int tid = threadIdx.x, lane = tid & 63, w = tid >> 6;
  const int quad = lane >> 4, l15 = lane & 15;

  __shared__ __align__(16) short Ks[3][64 * 64];   // [key][feature], chunk-swizzled
  __shared__ __align__(16) short Vs[3][64 * 64];   // [d][slot], chunk-swizzled

  const int qbase = qt * 128 + w * 16;   // frag0 rows qbase+l15, frag1 +64
  const short* qb0 = Q + ((long)(b * S_ + qbase + l15)) * (NH_ * HD_) + h * HD_;
  const short* qb1 = qb0 + 64L * (NH_ * HD_);
  const bf16x8 aq00 = *(const bf16x8*)(qb0 + quad * 8);
  const bf16x8 aq01 = *(const bf16x8*)(qb0 + 32 + quad * 8);
  const bf16x8 aq10 = *(const bf16x8*)(qb1 + quad * 8);
  const bf16x8 aq11 = *(const bf16x8*)(qb1 + 32 + quad * 8);

  f32x4 o0[4], o1[4];
#pragma unroll
  for (int i = 0; i < 4; ++i) {
    o0[i] = f32x4{0.f, 0.f, 0.f, 0.f};
    o1[i] = f32x4{0.f, 0.f, 0.f, 0.f};
  }
  f32x4 li0 = f32x4{0.f, 0.f, 0.f, 0.f};
  f32x4 li1 = f32x4{0.f, 0.f, 0.f, 0.f};

  const short* kg = Km + ((long)(b * S_)) * (NKV_ * HD_) + hkv * HD_;
  const short* vg = Vt + ((long)((b * NKV_ + hkv) * HD_)) * S_;

  const int rK = tid >> 3;                       // 0..31 (second half adds 32)
  const int cC = (tid & 7) ^ (rK & 7);           // +32 preserves &7
  const short* kSrc = kg + (long)rK * (NKV_ * HD_) + cC * 8;
  const short* vSrc = vg + (long)rK * S_ + cC * 8;
  short* kDst = &Ks[0][tid * 8];
  short* vDst = &Vs[0][tid * 8];

  auto stage = [&](int buf, int kb) {
    const long ko = (long)kb * 64 * (NKV_ * HD_);
    const long vo = (long)kb * 64;
    const int bo = buf * 4096;
    gload_lds16(kSrc + ko,                      kDst + bo);
    gload_lds16(kSrc + ko + 32L * (NKV_ * HD_), kDst + bo + 2048);
    gload_lds16(vSrc + vo,                      vDst + bo);
    gload_lds16(vSrc + vo + 32L * S_,           vDst + bo + 2048);
  };

  stage(0, 0);
  if (kmax >= 1) stage(1, 1);

  const int thr = w * 16 + l15;   // diagonal mask threshold (key offset vs row)
  union U8 { uint32_t u[4]; bf16x8 v; };

  int cur = 0;
  for (int kb = 0; kb <= kmax; ++kb) {
    if (kb < kmax) asm volatile("s_waitcnt vmcnt(4)" ::: "memory");
    else           asm volatile("s_waitcnt vmcnt(0)" ::: "memory");
    asm volatile("s_barrier" ::: "memory");      // buf[cur] staged, prev reads done
    if (kb + 2 <= kmax) {
      int nb = cur + 2; if (nb >= 3) nb -= 3;
      stage(nb, kb + 2);                         // 2-deep prefetch
    }
    const short* Kb = &Ks[cur][0];
    const short* Vb = &Vs[cur][0];
    const bool doF0 = (kb != kmax);              // frag0 fully masked at kmax

    // ---- Sc^T = K·Q^T (K-frags shared across both q-fragments) ----
    f32x4 s0[4], s1[4];
    __builtin_amdgcn_s_setprio(1);
#pragma unroll
    for (int nt = 0; nt < 4; ++nt) {
      const int r = nt * 16 + l15;
      bf16x8 k0 = *(const bf16x8*)&Kb[(r * 8 + ((quad)     ^ (r & 7))) * 8];
      bf16x8 k1 = *(const bf16x8*)&Kb[(r * 8 + ((quad + 4) ^ (r & 7))) * 8];
      f32x4 t = f32x4{0.f, 0.f, 0.f, 0.f};
      t = MFMA16(k0, aq10, t);
      t = MFMA16(k1, aq11, t);
      s1[nt] = t;
      if (doF0) {
        f32x4 u = f32x4{0.f, 0.f, 0.f, 0.f};
        u = MFMA16(k0, aq00, u);
        u = MFMA16(k1, aq01, u);
        s0[nt] = u;
      }
    }
    __builtin_amdgcn_s_setprio(0);

    // ---- causal mask (diagonal tiles only) ----
    if (kb == kmax) {            // frag1 diagonal
#pragma unroll
      for (int nt = 0; nt < 4; ++nt) {
        const int base = nt * 16 + quad * 4;
#pragma unroll
        for (int rr = 0; rr < 4; ++rr)
          if (base + rr > thr) s1[nt][rr] = -1e30f;
      }
    }
    if (doF0 && kb == kmax - 1) {   // frag0 diagonal
#pragma unroll
      for (int nt = 0; nt < 4; ++nt) {
        const int base = nt * 16 + quad * 4;
#pragma unroll
        for (int rr = 0; rr < 4; ++rr)
          if (base + rr > thr) s0[nt][rr] = -1e30f;
      }
    }

    // ---- exp2 + pack to P^T B-fragments (registers only) ----
    U8 p0[2], p1[2];
#pragma unroll
    for (int kt = 0; kt < 2; ++kt) {
      float e0 = fast_exp2(s1[2 * kt][0]),     e1 = fast_exp2(s1[2 * kt][1]);
      float e2 = fast_exp2(s1[2 * kt][2]),     e3 = fast_exp2(s1[2 * kt][3]);
      float e4 = fast_exp2(s1[2 * kt + 1][0]), e5 = fast_exp2(s1[2 * kt + 1][1]);
      float e6 = fast_exp2(s1[2 * kt + 1][2]), e7 = fast_exp2(s1[2 * kt + 1][3]);
      p1[kt].u[0] = f2bf_pk(e0, e1);
      p1[kt].u[1] = f2bf_pk(e2, e3);
      p1[kt].u[2] = f2bf_pk(e4, e5);
      p1[kt].u[3] = f2bf_pk(e6, e7);
      li1 += f32x4{e0, e1, e2, e3};
      li1 += f32x4{e4, e5, e6, e7};
    }
    if (doF0) {
#pragma unroll
      for (int kt = 0; kt < 2; ++kt) {
        float e0 = fast_exp2(s0[2 * kt][0]),     e1 = fast_exp2(s0[2 * kt][1]);
        float e2 = fast_exp2(s0[2 * kt][2]),     e3 = fast_exp2(s0[2 * kt][3]);
        float e4 = fast_exp2(s0[2 * kt + 1][0]), e5 = fast_exp2(s0[2 * kt + 1][1]);
        float e6 = fast_exp2(s0[2 * kt + 1][2]), e7 = fast_exp2(s0[2 * kt + 1][3]);
        p0[kt].u[0] = f2bf_pk(e0, e1);
        p0[kt].u[1] = f2bf_pk(e2, e3);
        p0[kt].u[2] = f2bf_pk(e4, e5);
        p0[kt].u[3] = f2bf_pk(e6, e7);
        li0 += f32x4{e0, e1, e2, e3};
        li0 += f32x4{e4, e5, e6, e7};
      }
    }

    // ---- O^T += V^T · P^T (V A-frags shared across both q-fragments) ----
    __builtin_amdgcn_s_setprio(1);
#pragma unroll
    for (int kt = 0; kt < 2; ++kt) {
      bf16x8 vf[4];
#pragma unroll
      for (int dt = 0; dt < 4; ++dt)
        vf[dt] = *(const bf16x8*)&Vb[(dt * 16 + l15) * 64 +
                                     (((kt * 4 + quad) ^ (l15 & 7)) << 3)];
#pragma unroll
      for (int dt = 0; dt < 4; ++dt)
        o1[dt] = MFMA16(vf[dt], p1[kt].v, o1[dt]);
      if (doF0) {
#pragma unroll
        for (int dt = 0; dt < 4; ++dt)
          o0[dt] = MFMA16(vf[dt], p0[kt].v, o0[dt]);
      }
    }
    __builtin_amdgcn_s_setprio(0);

    asm volatile("s_waitcnt lgkmcnt(0)" ::: "memory");   // all LDS reads serviced
    ++cur; if (cur == 3) cur = 0;
  }

  // ---- epilogue: O^T C-layout -> lane holds qrow=l15, d = dt*16+quad*4+r ----
  auto epi = [&](f32x4 (&o)[4], const f32x4& li4, int qrow0) {
    float l = (li4[0] + li4[1]) + (li4[2] + li4[3]);
    l += __shfl_xor(l, 16, 64);
    l += __shfl_xor(l, 32, 64);
    float invl = 1.0f / l;
    long orow = (long)(b * S_ + qrow0 + l15);
#pragma unroll
    for (int dt = 0; dt < 4; ++dt) {
      uint2 st;
      st.x = f2bf_pk(o[dt][0] * invl, o[dt][1] * invl);
      st.y = f2bf_pk(o[dt][2] * invl, o[dt][3] * invl);
      *(uint2*)&O[orow * (NH_ * HD_) + h * HD_ + dt * 16 + quad * 4] = st;
    }
  };
  epi(o1, li1, qbase + 64);
  epi(o0, li0, qbase);
}

// ---------------- launch -------------------------------------------------------
extern "C" void kernel_launch(void* const* d_in, const int* in_sizes, int n_in,
                              void* d_out, int out_size, void* d_ws, size_t ws_size,
                              hipStream_t stream) {
  const float* hs = (const float*)d_in[0];
  const float* Wq = (const float*)d_in[1];
  const float* Wk = (const float*)d_in[2];
  const float* Wv = (const float*)d_in[3];
  const float* Wo = (const float*)d_in[4];
  float* out = (float*)d_out;

  char* p = (char*)d_ws;
  auto carve = [&](size_t elems) { short* r = (short*)p; p += elems * 2; return r; };
  short* Xb  = carve(8388608);   // hidden bf16 [4096,2048]
  short* Wqb = carve(4194304);
  short* Wkb = carve(1048576);
  short* Wvb = carve(1048576);
  short* Wob = carve(4194304);
  short* Qm  = carve(8388608);   // Q [4096,2048]
  short* Kmt = carve(2097152);   // K [4096,512]
  short* Vmt = carve(2097152);   // V [4096,512]
  short* Vtt = carve(2097152);   // V^T [B,KV,HD,S] (slot-permuted)
  short* Om  = carve(8388608);   // attn out [4096,2048]

  Cvt5Args ca{hs, Wq, Wk, Wv, Wo, Xb, Wqb, Wkb, Wvb, Wob};
  cvt5_kernel<<<CV4 / 256, 256, 0, stream>>>(ca);

  // Fused Q+K+V projections: 256^2 8-wave phase-split GEMM, grid (12,16)
  gemm_qkv256<<<dim3(12, 16), 512, 0, stream>>>(Xb, Wqb, Wkb, Wvb, Qm, Kmt, Vmt);

  rope_vtrans_kernel<<<ROPE_BLOCKS + 512, 256, 0, stream>>>(Qm, Kmt, Vmt, Vtt);

  // attention split into two independent bh halves (visibility + tail overlap)
  attn_kernel<<<dim3(16, 32, 1), 256, 0, stream>>>(Qm, Kmt, Vtt, Om, 0);
  attn_kernel<<<dim3(16, 32, 1), 256, 0, stream>>>(Qm, Kmt, Vtt, Om, 32);

  // Output projection with fp32 epilogue into d_out
  gemm_out<<<dim3(16, 32), 256, 0, stream>>>(Om, Wob, out);
}

// Round 6
// 325.148 us; speedup vs baseline: 1.0312x; 1.0223x over previous
//
#include <hip/hip_runtime.h>
#include <hip/hip_bf16.h>
#include <cstdint>
#include <cmath>

// Problem constants
#define B_   2
#define S_   2048
#define H_   2048
#define NH_  32
#define NKV_ 8
#define HD_  64
#define CSTR 3072   // row stride of the concatenated QKV output [4096, 3072]

using bf16x8 = __attribute__((ext_vector_type(8))) short;
using f32x4  = __attribute__((ext_vector_type(4))) float;

#define MFMA16(a, b, c) __builtin_amdgcn_mfma_f32_16x16x32_bf16((a), (b), (c), 0, 0, 0)

__device__ __forceinline__ short f2bf(float f) {   // round-nearest-even
  uint32_t u = __float_as_uint(f);
  uint32_t r = (u + 0x7fffu + ((u >> 16) & 1u)) >> 16;
  return (short)r;
}
__device__ __forceinline__ float bf2f(short s) {
  return __uint_as_float(((uint32_t)(uint16_t)s) << 16);
}
// packed 2xf32 -> 2xbf16 (hardware op when available)
__device__ __forceinline__ uint32_t f2bf_pk(float a, float b) {
#if __has_builtin(__builtin_amdgcn_cvt_pk_bf16_f32)
  auto r = __builtin_amdgcn_cvt_pk_bf16_f32(a, b);
  uint32_t u; __builtin_memcpy(&u, &r, sizeof(u));
  return u;
#else
  uint32_t ua = (__float_as_uint(a) + 0x8000u) >> 16;
  uint32_t ub = (__float_as_uint(b) + 0x8000u) >> 16;
  return ua | (ub << 16);
#endif
}
// raw v_exp_f32 (2^x)
__device__ __forceinline__ float fast_exp2(float x) {
#if __has_builtin(__builtin_amdgcn_exp2f)
  return __builtin_amdgcn_exp2f(x);
#else
  return exp2f(x);
#endif
}

__device__ __forceinline__ void gload_lds16(const void* g, void* l) {
  __builtin_amdgcn_global_load_lds((const __attribute__((address_space(1))) void*)g,
                                   (__attribute__((address_space(3))) void*)l, 16, 0, 0);
}

// ---------------- fused fp32 -> bf16 convert for all 5 tensors ------------------
struct Cvt5Args {
  const float *s0, *s1, *s2, *s3, *s4;
  short *d0, *d1, *d2, *d3, *d4;
};
#define CV0 2097152             // hs      (float4 units)
#define CV1 (CV0 + 1048576)     // Wq
#define CV2 (CV1 + 262144)      // Wk
#define CV3 (CV2 + 262144)      // Wv
#define CV4 (CV3 + 1048576)     // Wo -> total 4718592
__global__ void cvt5_kernel(Cvt5Args a) {
  int i = blockIdx.x * blockDim.x + threadIdx.x;
  const float* s; short* d; int off;
  if      (i < CV0) { s = a.s0; d = a.d0; off = i; }
  else if (i < CV1) { s = a.s1; d = a.d1; off = i - CV0; }
  else if (i < CV2) { s = a.s2; d = a.d2; off = i - CV1; }
  else if (i < CV3) { s = a.s3; d = a.d3; off = i - CV2; }
  else              { s = a.s4; d = a.d4; off = i - CV3; }
  const float4 v = ((const float4*)s)[off];
  uint2 o;
  o.x = (uint32_t)(uint16_t)f2bf(v.x) | ((uint32_t)(uint16_t)f2bf(v.y) << 16);
  o.y = (uint32_t)(uint16_t)f2bf(v.z) | ((uint32_t)(uint16_t)f2bf(v.w) << 16);
  ((uint2*)d)[off] = o;
}

// ---------------- 256x192 QKV-cat GEMM: grid 16x16 = 256 blocks = 1/CU ---------
// Ccat[4096,3072] = X[4096,2048] * Wcat[3072,2048]^T, Wcat = [Wq;Wk;Wv] rows
// (contiguous workspace carve). BK=64, 512 threads = 8 waves (2M x 4N); per
// wave 128x48 output = 8x3 16x16 frags (96 acc VGPR). LDS 112 KiB (A 2x32K,
// B 2x24K). Protocol verified in R5's 256^2 kernel: stage(t+1) at phase 0 of
// tile t into the other slot; mid barrier between mf-half phases; end-of-tile
// vmcnt(0)+lgkmcnt(0)+barrier releases slot t&1 with slot (t+1)&1 staged.
// XOR swizzle unchanged (wn multiples of 48 are multiples of 16, so row&7 ==
// l15&7 on every ds_read). K-order per acc element identical to previous
// rounds -> bit-identical output.
__global__ __launch_bounds__(512, 2) void gemm_qkvcat(
    const short* __restrict__ A, const short* __restrict__ Bcat,
    short* __restrict__ Ccat)
{
  __shared__ __align__(16) short As[2][256 * 64];   // 64 KiB
  __shared__ __align__(16) short Bs[2][192 * 64];   // 48 KiB

  const long tileM = (long)blockIdx.y * 256;
  const long tileN = (long)blockIdx.x * 192;
  const int  K = 2048;

  const int tid  = threadIdx.x;
  const int lane = tid & 63;
  const int quad = lane >> 4;
  const int l15  = lane & 15;
  const int wave = tid >> 6;
  const int wm   = (wave >> 2) * 128;     // 0 / 128
  const int wn   = (wave & 3) * 48;       // 0..144 (multiple of 16)
  const int xsw  = l15 & 7;

  f32x4 acc[8][3];
#pragma unroll
  for (int i = 0; i < 8; ++i)
#pragma unroll
    for (int j = 0; j < 3; ++j) acc[i][j] = f32x4{0.f, 0.f, 0.f, 0.f};

  // Staging: thread c = tid + 512p covers row c>>3, LDS chunk c&7 (linear dest).
  // Global source chunk = swizzle inverse. A: 4 passes (256 rows), B: 3 (192).
  const int cS = (tid & 7) ^ ((tid >> 3) & 7);
  const short* gA[4]; const short* gB[3];
#pragma unroll
  for (int p = 0; p < 4; ++p)
    gA[p] = A + (tileM + (tid >> 3) + 64 * p) * K + cS * 8;
#pragma unroll
  for (int p = 0; p < 3; ++p)
    gB[p] = Bcat + (tileN + (tid >> 3) + 64 * p) * K + cS * 8;

  auto stage = [&](int buf, int t) {
    const long ko = (long)t * 64;
    short* la = &As[buf][0];
    short* lb = &Bs[buf][0];
#pragma unroll
    for (int p = 0; p < 4; ++p)
      gload_lds16(gA[p] + ko, la + (tid + p * 512) * 8);
#pragma unroll
    for (int p = 0; p < 3; ++p)
      gload_lds16(gB[p] + ko, lb + (tid + p * 512) * 8);
  };

  const int NT = K / 64;                       // 32
  stage(0, 0);
  asm volatile("s_waitcnt vmcnt(0)" ::: "memory");
  asm volatile("s_barrier" ::: "memory");

  bf16x8 af[4][2], bfr[3][2];

  auto ldA = [&](const short* Ab, int half) {
#pragma unroll
    for (int m = 0; m < 4; ++m) {
      const int r = wm + (half * 4 + m) * 16 + l15;
#pragma unroll
      for (int kk = 0; kk < 2; ++kk)
        af[m][kk] = *(const bf16x8*)&Ab[r * 64 + (((kk * 4 + quad) ^ xsw) << 3)];
    }
  };
  auto ldB = [&](const short* Bb) {
#pragma unroll
    for (int n = 0; n < 3; ++n) {
      const int r = wn + n * 16 + l15;
#pragma unroll
      for (int kk = 0; kk < 2; ++kk)
        bfr[n][kk] = *(const bf16x8*)&Bb[r * 64 + (((kk * 4 + quad) ^ xsw) << 3)];
    }
  };
  auto mma = [&](int half) {
    __builtin_amdgcn_s_setprio(1);
#pragma unroll
    for (int m = 0; m < 4; ++m)
#pragma unroll
      for (int n = 0; n < 3; ++n)
#pragma unroll
        for (int kk = 0; kk < 2; ++kk)
          acc[half * 4 + m][n] = MFMA16(af[m][kk], bfr[n][kk], acc[half * 4 + m][n]);
    __builtin_amdgcn_s_setprio(0);
  };

  for (int t = 0; t < NT; ++t) {
    const int cur = t & 1;
    const short* Ab = &As[cur][0];
    const short* Bb = &Bs[cur][0];

    // phase 0: stage next tile, mf-half 0 (B loaded once, reused in half 1)
    if (t + 1 < NT) stage(cur ^ 1, t + 1);
    ldB(Bb); ldA(Ab, 0); mma(0);
    asm volatile("s_barrier" ::: "memory");
    // phase 1: mf-half 1
    ldA(Ab, 1); mma(1);
    asm volatile("s_waitcnt vmcnt(0)" ::: "memory");    // next-tile DMA landed
    asm volatile("s_waitcnt lgkmcnt(0)" ::: "memory");  // my reads of slot cur done
    asm volatile("s_barrier" ::: "memory");             // release slot cur
  }

#pragma unroll
  for (int i = 0; i < 8; ++i)
#pragma unroll
    for (int j = 0; j < 3; ++j)
#pragma unroll
      for (int r = 0; r < 4; ++r) {
        long row = tileM + wm + i * 16 + quad * 4 + r;
        long col = tileN + wn + j * 16 + l15;
        Ccat[row * CSTR + col] = f2bf(acc[i][j][r]);
      }
}

// ---------------- 256x128 GEMM (output projection): grid 16x16 = 256 blocks ----
// Cf[4096,2048] = A[4096,2048] * Wo[2048,2048]^T, fp32 epilogue. Same protocol.
// Per wave 128x32 = 8x2 frags (64 acc VGPR). LDS 96 KiB.
__global__ __launch_bounds__(512, 2) void gemm_out(
    const short* __restrict__ A, const short* __restrict__ Bm,
    float* __restrict__ Cf)
{
  __shared__ __align__(16) short As[2][256 * 64];   // 64 KiB
  __shared__ __align__(16) short Bs[2][128 * 64];   // 32 KiB

  const int N = 2048, K = 2048;
  const long tileM = (long)blockIdx.y * 256;
  const long tileN = (long)blockIdx.x * 128;

  const int tid  = threadIdx.x;
  const int lane = tid & 63;
  const int quad = lane >> 4;
  const int l15  = lane & 15;
  const int wave = tid >> 6;
  const int wm   = (wave >> 2) * 128;
  const int wn   = (wave & 3) * 32;
  const int xsw  = l15 & 7;

  f32x4 acc[8][2];
#pragma unroll
  for (int i = 0; i < 8; ++i)
#pragma unroll
    for (int j = 0; j < 2; ++j) acc[i][j] = f32x4{0.f, 0.f, 0.f, 0.f};

  const int cS = (tid & 7) ^ ((tid >> 3) & 7);
  const short* gA[4]; const short* gB[2];
#pragma unroll
  for (int p = 0; p < 4; ++p)
    gA[p] = A + (tileM + (tid >> 3) + 64 * p) * K + cS * 8;
#pragma unroll
  for (int p = 0; p < 2; ++p)
    gB[p] = Bm + (tileN + (tid >> 3) + 64 * p) * K + cS * 8;

  auto stage = [&](int buf, int t) {
    const long ko = (long)t * 64;
    short* la = &As[buf][0];
    short* lb = &Bs[buf][0];
#pragma unroll
    for (int p = 0; p < 4; ++p)
      gload_lds16(gA[p] + ko, la + (tid + p * 512) * 8);
#pragma unroll
    for (int p = 0; p < 2; ++p)
      gload_lds16(gB[p] + ko, lb + (tid + p * 512) * 8);
  };

  const int NT = K / 64;
  stage(0, 0);
  asm volatile("s_waitcnt vmcnt(0)" ::: "memory");
  asm volatile("s_barrier" ::: "memory");

  bf16x8 af[4][2], bfr[2][2];

  auto ldA = [&](const short* Ab, int half) {
#pragma unroll
    for (int m = 0; m < 4; ++m) {
      const int r = wm + (half * 4 + m) * 16 + l15;
#pragma unroll
      for (int kk = 0; kk < 2; ++kk)
        af[m][kk] = *(const bf16x8*)&Ab[r * 64 + (((kk * 4 + quad) ^ xsw) << 3)];
    }
  };
  auto ldB = [&](const short* Bb) {
#pragma unroll
    for (int n = 0; n < 2; ++n) {
      const int r = wn + n * 16 + l15;
#pragma unroll
      for (int kk = 0; kk < 2; ++kk)
        bfr[n][kk] = *(const bf16x8*)&Bb[r * 64 + (((kk * 4 + quad) ^ xsw) << 3)];
    }
  };
  auto mma = [&](int half) {
    __builtin_amdgcn_s_setprio(1);
#pragma unroll
    for (int m = 0; m < 4; ++m)
#pragma unroll
      for (int n = 0; n < 2; ++n)
#pragma unroll
        for (int kk = 0; kk < 2; ++kk)
          acc[half * 4 + m][n] = MFMA16(af[m][kk], bfr[n][kk], acc[half * 4 + m][n]);
    __builtin_amdgcn_s_setprio(0);
  };

  for (int t = 0; t < NT; ++t) {
    const int cur = t & 1;
    const short* Ab = &As[cur][0];
    const short* Bb = &Bs[cur][0];

    if (t + 1 < NT) stage(cur ^ 1, t + 1);
    ldB(Bb); ldA(Ab, 0); mma(0);
    asm volatile("s_barrier" ::: "memory");
    ldA(Ab, 1); mma(1);
    asm volatile("s_waitcnt vmcnt(0)" ::: "memory");
    asm volatile("s_waitcnt lgkmcnt(0)" ::: "memory");
    asm volatile("s_barrier" ::: "memory");
  }

#pragma unroll
  for (int i = 0; i < 8; ++i)
#pragma unroll
    for (int j = 0; j < 2; ++j)
#pragma unroll
      for (int r = 0; r < 4; ++r) {
        long row = tileM + wm + i * 16 + quad * 4 + r;
        long col = tileN + wn + j * 16 + l15;
        Cf[row * N + col] = acc[i][j][r];
      }
}

// ---------------- fused RoPE (Q,K in-place in Ccat) + V transpose ---------------
// Q = Ccat cols 0..2047, K = cols 2048..2559, V = cols 2560..3071 (stride 3072).
// Vectorized x8; math identical to previous (bit-identical output).
// Q scaled by (1/8)*log2(e); V^T written slot-permuted for the attn PV A-frag.
#define ROPE_BLOCKS 2560          // Q: 2048 blocks, K: 512 blocks (x8 vectorized)
__global__ void rope_vtrans_kernel(short* __restrict__ Ccat, short* __restrict__ Vt) {
  __shared__ short tile[64][65];
  if (blockIdx.x < ROPE_BLOCKS) {
    const int QT = (B_ * S_) * NH_ * 4;  // 524288 Q threads (4 groups of 8 per head)
    int t = blockIdx.x * blockDim.x + threadIdx.x;
    long base; int g; float scale; int row;
    if (t < QT) {
      row = t >> 7; int rem = t & 127, head = rem >> 2; g = rem & 3;
      base = (long)row * CSTR + head * HD_;
      scale = 0.125f * 1.44269504f;
    } else {
      int t2 = t - QT;
      row = t2 >> 5; int rem = t2 & 31, head = rem >> 2; g = rem & 3;
      base = (long)row * CSTR + 2048 + head * HD_;
      scale = 1.0f;
    }
    const int s = row & (S_ - 1);
    const int i0 = g * 8;
    union V8 { bf16x8 v; short e[8]; };
    V8 x0, x1, y0, y1;
    x0.v = *(const bf16x8*)&Ccat[base + i0];
    x1.v = *(const bf16x8*)&Ccat[base + i0 + 32];
#pragma unroll
    for (int j = 0; j < 8; ++j) {
      const int i = i0 + j;
      float invr = exp2f((float)i * -0.41524101f) * 0.15915494309f;
      float rev = (float)s * invr;
      rev -= floorf(rev);
      float ar = rev * 6.28318530718f;
      float c = __cosf(ar), sn = __sinf(ar);
      float a = bf2f(x0.e[j]);
      float b = bf2f(x1.e[j]);
      y0.e[j] = f2bf((a * c - b * sn) * scale);
      y1.e[j] = f2bf((b * c + a * sn) * scale);
    }
    *(bf16x8*)&Ccat[base + i0]      = y0.v;
    *(bf16x8*)&Ccat[base + i0 + 32] = y1.v;
  } else {
    int blk = blockIdx.x - ROPE_BLOCKS;
    int s0 = (blk & 31) * 64;
    int h  = (blk >> 5) & 7;
    int b  = blk >> 8;
    int tid = threadIdx.x;
#pragma unroll
    for (int it = 0; it < 16; ++it) {
      int idx = tid + it * 256;
      int r = idx >> 6, c = idx & 63;
      tile[r][c] = Ccat[((long)(b * S_ + s0 + r)) * CSTR + 2560 + h * HD_ + c];
    }
    __syncthreads();
#pragma unroll
    for (int it = 0; it < 16; ++it) {
      int idx = tid + it * 256;
      int d = idx >> 6, s = idx & 63;
      int slot = (s & 0x20) | (((s >> 2) & 3) << 3) | (((s >> 4) & 1) << 2) | (s & 3);
      Vt[((long)((b * NKV_ + h) * HD_ + d)) * S_ + s0 + slot] = tile[s][d];
    }
  }
}

// ---------------- Flash attention (causal, GQA), transposed-score form ----------
// 128 q-rows per block (two 16-row fragments per wave). Grid (16, 32) x2
// launches (bh halves). Q/K read from Ccat (stride 3072); V^T from Vt.
// 3-buffer, 2-deep prefetch with counted vmcnt(4); one barrier per iteration.
__global__ __launch_bounds__(256, 3) void attn_kernel(
    const short* __restrict__ Ccat, const short* __restrict__ Vt,
    short* __restrict__ O, int bh0)
{
  const int qt = 15 - (int)blockIdx.x;   // 128-row q-tile, long blocks first
  const int kmax = 2 * qt + 1;           // last 64-key tile index
  const int bh = blockIdx.y + bh0;
  const int b = bh >> 5, h = bh & 31, hkv = h >> 2;
  const int tid = threadIdx.x, lane = tid & 63, w = tid >> 6;
  const int quad = lane >> 4, l15 = lane & 15;

  __shared__ __align__(16) short Ks[3][64 * 64];   // [key][feature], chunk-swizzled
  __shared__ __align__(16) short Vs[3][64 * 64];   // [d][slot], chunk-swizzled

  const int qbase = qt * 128 + w * 16;   // frag0 rows qbase+l15, frag1 +64
  const short* qb0 = Ccat + ((long)(b * S_ + qbase + l15)) * CSTR + h * HD_;
  const short* qb1 = qb0 + 64L * CSTR;
  const bf16x8 aq00 = *(const bf16x8*)(qb0 + quad * 8);
  const bf16x8 aq01 = *(const bf16x8*)(qb0 + 32 + quad * 8);
  const bf16x8 aq10 = *(const bf16x8*)(qb1 + quad * 8);
  const bf16x8 aq11 = *(const bf16x8*)(qb1 + 32 + quad * 8);

  f32x4 o0[4], o1[4];
#pragma unroll
  for (int i = 0; i < 4; ++i) {
    o0[i] = f32x4{0.f, 0.f, 0.f, 0.f};
    o1[i] = f32x4{0.f, 0.f, 0.f, 0.f};
  }
  f32x4 li0 = f32x4{0.f, 0.f, 0.f, 0.f};
  f32x4 li1 = f32x4{0.f, 0.f, 0.f, 0.f};

  const short* kg = Ccat + ((long)(b * S_)) * CSTR + 2048 + hkv * HD_;
  const short* vg = Vt + ((long)((b * NKV_ + hkv) * HD_)) * S_;

  const int rK = tid >> 3;                       // 0..31 (second half adds 32)
  const int cC = (tid & 7) ^ (rK & 7);           // +32 preserves &7
  const short* kSrc = kg + (long)rK * CSTR + cC * 8;
  const short* vSrc = vg + (long)rK * S_ + cC * 8;
  short* kDst = &Ks[0][tid * 8];
  short* vDst = &Vs[0][tid * 8];

  auto stage = [&](int buf, int kb) {
    const long ko = (long)kb * 64 * CSTR;
    const long vo = (long)kb * 64;
    const int bo = buf * 4096;
    gload_lds16(kSrc + ko,              kDst + bo);
    gload_lds16(kSrc + ko + 32L * CSTR, kDst + bo + 2048);
    gload_lds16(vSrc + vo,              vDst + bo);
    gload_lds16(vSrc + vo + 32L * S_,   vDst + bo + 2048);
  };

  stage(0, 0);
  if (kmax >= 1) stage(1, 1);

  const int thr = w * 16 + l15;   // diagonal mask threshold (key offset vs row)
  union U8 { uint32_t u[4]; bf16x8 v; };

  int cur = 0;
  for (int kb = 0; kb <= kmax; ++kb) {
    if (kb < kmax) asm volatile("s_waitcnt vmcnt(4)" ::: "memory");
    else           asm volatile("s_waitcnt vmcnt(0)" ::: "memory");
    asm volatile("s_barrier" ::: "memory");      // buf[cur] staged, prev reads done
    if (kb + 2 <= kmax) {
      int nb = cur + 2; if (nb >= 3) nb -= 3;
      stage(nb, kb + 2);                         // 2-deep prefetch
    }
    const short* Kb = &Ks[cur][0];
    const short* Vb = &Vs[cur][0];
    const bool doF0 = (kb != kmax);              // frag0 fully masked at kmax

    // ---- Sc^T = K·Q^T (K-frags shared across both q-fragments) ----
    f32x4 s0[4], s1[4];
    __builtin_amdgcn_s_setprio(1);
#pragma unroll
    for (int nt = 0; nt < 4; ++nt) {
      const int r = nt * 16 + l15;
      bf16x8 k0 = *(const bf16x8*)&Kb[(r * 8 + ((quad)     ^ (r & 7))) * 8];
      bf16x8 k1 = *(const bf16x8*)&Kb[(r * 8 + ((quad + 4) ^ (r & 7))) * 8];
      f32x4 t = f32x4{0.f, 0.f, 0.f, 0.f};
      t = MFMA16(k0, aq10, t);
      t = MFMA16(k1, aq11, t);
      s1[nt] = t;
      if (doF0) {
        f32x4 u = f32x4{0.f, 0.f, 0.f, 0.f};
        u = MFMA16(k0, aq00, u);
        u = MFMA16(k1, aq01, u);
        s0[nt] = u;
      }
    }
    __builtin_amdgcn_s_setprio(0);

    // ---- causal mask (diagonal tiles only) ----
    if (kb == kmax) {            // frag1 diagonal
#pragma unroll
      for (int nt = 0; nt < 4; ++nt) {
        const int base = nt * 16 + quad * 4;
#pragma unroll
        for (int rr = 0; rr < 4; ++rr)
          if (base + rr > thr) s1[nt][rr] = -1e30f;
      }
    }
    if (doF0 && kb == kmax - 1) {   // frag0 diagonal
#pragma unroll
      for (int nt = 0; nt < 4; ++nt) {
        const int base = nt * 16 + quad * 4;
#pragma unroll
        for (int rr = 0; rr < 4; ++rr)
          if (base + rr > thr) s0[nt][rr] = -1e30f;
      }
    }

    // ---- exp2 + pack to P^T B-fragments (registers only) ----
    U8 p0[2], p1[2];
#pragma unroll
    for (int kt = 0; kt < 2; ++kt) {
      float e0 = fast_exp2(s1[2 * kt][0]),     e1 = fast_exp2(s1[2 * kt][1]);
      float e2 = fast_exp2(s1[2 * kt][2]),     e3 = fast_exp2(s1[2 * kt][3]);
      float e4 = fast_exp2(s1[2 * kt + 1][0]), e5 = fast_exp2(s1[2 * kt + 1][1]);
      float e6 = fast_exp2(s1[2 * kt + 1][2]), e7 = fast_exp2(s1[2 * kt + 1][3]);
      p1[kt].u[0] = f2bf_pk(e0, e1);
      p1[kt].u[1] = f2bf_pk(e2, e3);
      p1[kt].u[2] = f2bf_pk(e4, e5);
      p1[kt].u[3] = f2bf_pk(e6, e7);
      li1 += f32x4{e0, e1, e2, e3};
      li1 += f32x4{e4, e5, e6, e7};
    }
    if (doF0) {
#pragma unroll
      for (int kt = 0; kt < 2; ++kt) {
        float e0 = fast_exp2(s0[2 * kt][0]),     e1 = fast_exp2(s0[2 * kt][1]);
        float e2 = fast_exp2(s0[2 * kt][2]),     e3 = fast_exp2(s0[2 * kt][3]);
        float e4 = fast_exp2(s0[2 * kt + 1][0]), e5 = fast_exp2(s0[2 * kt + 1][1]);
        float e6 = fast_exp2(s0[2 * kt + 1][2]), e7 = fast_exp2(s0[2 * kt + 1][3]);
        p0[kt].u[0] = f2bf_pk(e0, e1);
        p0[kt].u[1] = f2bf_pk(e2, e3);
        p0[kt].u[2] = f2bf_pk(e4, e5);
        p0[kt].u[3] = f2bf_pk(e6, e7);
        li0 += f32x4{e0, e1, e2, e3};
        li0 += f32x4{e4, e5, e6, e7};
      }
    }

    // ---- O^T += V^T · P^T (V A-frags shared across both q-fragments) ----
    __builtin_amdgcn_s_setprio(1);
#pragma unroll
    for (int kt = 0; kt < 2; ++kt) {
      bf16x8 vf[4];
#pragma unroll
      for (int dt = 0; dt < 4; ++dt)
        vf[dt] = *(const bf16x8*)&Vb[(dt * 16 + l15) * 64 +
                                     (((kt * 4 + quad) ^ (l15 & 7)) << 3)];
#pragma unroll
      for (int dt = 0; dt < 4; ++dt)
        o1[dt] = MFMA16(vf[dt], p1[kt].v, o1[dt]);
      if (doF0) {
#pragma unroll
        for (int dt = 0; dt < 4; ++dt)
          o0[dt] = MFMA16(vf[dt], p0[kt].v, o0[dt]);
      }
    }
    __builtin_amdgcn_s_setprio(0);

    asm volatile("s_waitcnt lgkmcnt(0)" ::: "memory");   // all LDS reads serviced
    ++cur; if (cur == 3) cur = 0;
  }

  // ---- epilogue: O^T C-layout -> lane holds qrow=l15, d = dt*16+quad*4+r ----
  auto epi = [&](f32x4 (&o)[4], const f32x4& li4, int qrow0) {
    float l = (li4[0] + li4[1]) + (li4[2] + li4[3]);
    l += __shfl_xor(l, 16, 64);
    l += __shfl_xor(l, 32, 64);
    float invl = 1.0f / l;
    long orow = (long)(b * S_ + qrow0 + l15);
#pragma unroll
    for (int dt = 0; dt < 4; ++dt) {
      uint2 st;
      st.x = f2bf_pk(o[dt][0] * invl, o[dt][1] * invl);
      st.y = f2bf_pk(o[dt][2] * invl, o[dt][3] * invl);
      *(uint2*)&O[orow * (NH_ * HD_) + h * HD_ + dt * 16 + quad * 4] = st;
    }
  };
  epi(o1, li1, qbase + 64);
  epi(o0, li0, qbase);
}

// ---------------- launch -------------------------------------------------------
extern "C" void kernel_launch(void* const* d_in, const int* in_sizes, int n_in,
                              void* d_out, int out_size, void* d_ws, size_t ws_size,
                              hipStream_t stream) {
  const float* hs = (const float*)d_in[0];
  const float* Wq = (const float*)d_in[1];
  const float* Wk = (const float*)d_in[2];
  const float* Wv = (const float*)d_in[3];
  const float* Wo = (const float*)d_in[4];
  float* out = (float*)d_out;

  char* p = (char*)d_ws;
  auto carve = [&](size_t elems) { short* r = (short*)p; p += elems * 2; return r; };
  short* Xb   = carve(8388608);    // hidden bf16 [4096,2048]
  short* Wcat = carve(6291456);    // [Wq;Wk;Wv] rows -> [3072,2048]
  short* Wob  = carve(4194304);
  short* Ccat = carve(12582912);   // QKV-cat [4096,3072]
  short* Vtt  = carve(2097152);    // V^T [B,KV,HD,S] (slot-permuted)
  short* Om   = carve(8388608);    // attn out [4096,2048]

  short* Wqb = Wcat;               // rows 0..2047
  short* Wkb = Wcat + 4194304;     // rows 2048..2559
  short* Wvb = Wcat + 5242880;     // rows 2560..3071

  Cvt5Args ca{hs, Wq, Wk, Wv, Wo, Xb, Wqb, Wkb, Wvb, Wob};
  cvt5_kernel<<<CV4 / 256, 256, 0, stream>>>(ca);

  // QKV-cat projection: 256x192 tiles, grid 16x16 = 256 blocks = 1/CU exactly
  gemm_qkvcat<<<dim3(16, 16), 512, 0, stream>>>(Xb, Wcat, Ccat);

  rope_vtrans_kernel<<<ROPE_BLOCKS + 512, 256, 0, stream>>>(Ccat, Vtt);

  // attention split into two independent bh halves
  attn_kernel<<<dim3(16, 32, 1), 256, 0, stream>>>(Ccat, Vtt, Om, 0);
  attn_kernel<<<dim3(16, 32, 1), 256, 0, stream>>>(Ccat, Vtt, Om, 32);

  // Output projection: 256x128 tiles, grid 16x16 = 256 blocks = 1/CU exactly
  gemm_out<<<dim3(16, 16), 512, 0, stream>>>(Om, Wob, out);
}

// Round 7
// 301.946 us; speedup vs baseline: 1.1104x; 1.0768x over previous
//
#include <hip/hip_runtime.h>
#include <hip/hip_bf16.h>
#include <cstdint>
#include <cmath>

// Problem constants
#define B_   2
#define S_   2048
#define H_   2048
#define NH_  32
#define NKV_ 8
#define HD_  64
#define CSTR 3072   // row stride of the concatenated QKV output [4096, 3072]

using bf16x8 = __attribute__((ext_vector_type(8))) short;
using f32x4  = __attribute__((ext_vector_type(4))) float;

#define MFMA16(a, b, c) __builtin_amdgcn_mfma_f32_16x16x32_bf16((a), (b), (c), 0, 0, 0)

__device__ __forceinline__ short f2bf(float f) {   // round-nearest-even
  uint32_t u = __float_as_uint(f);
  uint32_t r = (u + 0x7fffu + ((u >> 16) & 1u)) >> 16;
  return (short)r;
}
__device__ __forceinline__ float bf2f(short s) {
  return __uint_as_float(((uint32_t)(uint16_t)s) << 16);
}
// packed 2xf32 -> 2xbf16 (hardware op when available)
__device__ __forceinline__ uint32_t f2bf_pk(float a, float b) {
#if __has_builtin(__builtin_amdgcn_cvt_pk_bf16_f32)
  auto r = __builtin_amdgcn_cvt_pk_bf16_f32(a, b);
  uint32_t u; __builtin_memcpy(&u, &r, sizeof(u));
  return u;
#else
  uint32_t ua = (__float_as_uint(a) + 0x8000u) >> 16;
  uint32_t ub = (__float_as_uint(b) + 0x8000u) >> 16;
  return ua | (ub << 16);
#endif
}
// raw v_exp_f32 (2^x)
__device__ __forceinline__ float fast_exp2(float x) {
#if __has_builtin(__builtin_amdgcn_exp2f)
  return __builtin_amdgcn_exp2f(x);
#else
  return exp2f(x);
#endif
}

__device__ __forceinline__ void gload_lds16(const void* g, void* l) {
  __builtin_amdgcn_global_load_lds((const __attribute__((address_space(1))) void*)g,
                                   (__attribute__((address_space(3))) void*)l, 16, 0, 0);
}

// ---------------- fused fp32 -> bf16 convert for all 5 tensors ------------------
struct Cvt5Args {
  const float *s0, *s1, *s2, *s3, *s4;
  short *d0, *d1, *d2, *d3, *d4;
};
#define CV0 2097152             // hs      (float4 units)
#define CV1 (CV0 + 1048576)     // Wq
#define CV2 (CV1 + 262144)      // Wk
#define CV3 (CV2 + 262144)      // Wv
#define CV4 (CV3 + 1048576)     // Wo -> total 4718592
__global__ void cvt5_kernel(Cvt5Args a) {
  int i = blockIdx.x * blockDim.x + threadIdx.x;
  const float* s; short* d; int off;
  if      (i < CV0) { s = a.s0; d = a.d0; off = i; }
  else if (i < CV1) { s = a.s1; d = a.d1; off = i - CV0; }
  else if (i < CV2) { s = a.s2; d = a.d2; off = i - CV1; }
  else if (i < CV3) { s = a.s3; d = a.d3; off = i - CV2; }
  else              { s = a.s4; d = a.d4; off = i - CV3; }
  const float4 v = ((const float4*)s)[off];
  uint2 o;
  o.x = (uint32_t)(uint16_t)f2bf(v.x) | ((uint32_t)(uint16_t)f2bf(v.y) << 16);
  o.y = (uint32_t)(uint16_t)f2bf(v.z) | ((uint32_t)(uint16_t)f2bf(v.w) << 16);
  ((uint2*)d)[off] = o;
}

// ---------------- 128x192 QKV-cat GEMM: grid 16x32 = 512 blocks = 2/CU ---------
// Ccat[4096,3072] = X[4096,2048] * Wcat[3072,2048]^T. BK=64, 512 threads =
// 8 waves (2M x 4N); per wave 64x48 output = 4x3 16x16 frags (48 acc VGPR).
// LDS = A 2x16K + B 2x24K = EXACTLY 80 KiB -> 2 blocks/CU (4 waves/SIMD).
// Rationale (R6 post-mortem): at 1 block/CU all 8 waves drain vmcnt(0)+barrier
// in lockstep with nothing to backfill; a second independent block per CU
// overlaps its MFMA phases with this block's drain (m114 mechanism).
// Protocol & XOR swizzle verbatim from the R6-verified kernel; K-accumulation
// order per output element unchanged -> bit-identical numerics.
__global__ __launch_bounds__(512, 4) void gemm_qkvcat(
    const short* __restrict__ A, const short* __restrict__ Bcat,
    short* __restrict__ Ccat)
{
  __shared__ __align__(16) short As[2][128 * 64];   // 32 KiB
  __shared__ __align__(16) short Bs[2][192 * 64];   // 48 KiB

  const long tileM = (long)blockIdx.y * 128;
  const long tileN = (long)blockIdx.x * 192;
  const int  K = 2048;

  const int tid  = threadIdx.x;
  const int lane = tid & 63;
  const int quad = lane >> 4;
  const int l15  = lane & 15;
  const int wave = tid >> 6;
  const int wm   = (wave >> 2) * 64;      // 0 / 64
  const int wn   = (wave & 3) * 48;       // 0..144 (multiple of 16)
  const int xsw  = l15 & 7;

  f32x4 acc[4][3];
#pragma unroll
  for (int i = 0; i < 4; ++i)
#pragma unroll
    for (int j = 0; j < 3; ++j) acc[i][j] = f32x4{0.f, 0.f, 0.f, 0.f};

  // Staging: thread c = tid + 512p covers row c>>3, LDS chunk c&7 (linear dest).
  // Global source chunk = swizzle inverse. A: 2 passes (128 rows), B: 3 (192).
  const int cS = (tid & 7) ^ ((tid >> 3) & 7);
  const short* gA[2]; const short* gB[3];
#pragma unroll
  for (int p = 0; p < 2; ++p)
    gA[p] = A + (tileM + (tid >> 3) + 64 * p) * K + cS * 8;
#pragma unroll
  for (int p = 0; p < 3; ++p)
    gB[p] = Bcat + (tileN + (tid >> 3) + 64 * p) * K + cS * 8;

  auto stage = [&](int buf, int t) {
    const long ko = (long)t * 64;
    short* la = &As[buf][0];
    short* lb = &Bs[buf][0];
#pragma unroll
    for (int p = 0; p < 2; ++p)
      gload_lds16(gA[p] + ko, la + (tid + p * 512) * 8);
#pragma unroll
    for (int p = 0; p < 3; ++p)
      gload_lds16(gB[p] + ko, lb + (tid + p * 512) * 8);
  };

  const int NT = K / 64;                       // 32
  stage(0, 0);
  asm volatile("s_waitcnt vmcnt(0)" ::: "memory");
  asm volatile("s_barrier" ::: "memory");

  bf16x8 af[2][2], bfr[3][2];

  auto ldA = [&](const short* Ab, int half) {
#pragma unroll
    for (int m = 0; m < 2; ++m) {
      const int r = wm + (half * 2 + m) * 16 + l15;
#pragma unroll
      for (int kk = 0; kk < 2; ++kk)
        af[m][kk] = *(const bf16x8*)&Ab[r * 64 + (((kk * 4 + quad) ^ xsw) << 3)];
    }
  };
  auto ldB = [&](const short* Bb) {
#pragma unroll
    for (int n = 0; n < 3; ++n) {
      const int r = wn + n * 16 + l15;
#pragma unroll
      for (int kk = 0; kk < 2; ++kk)
        bfr[n][kk] = *(const bf16x8*)&Bb[r * 64 + (((kk * 4 + quad) ^ xsw) << 3)];
    }
  };
  auto mma = [&](int half) {
    __builtin_amdgcn_s_setprio(1);
#pragma unroll
    for (int m = 0; m < 2; ++m)
#pragma unroll
      for (int n = 0; n < 3; ++n)
#pragma unroll
        for (int kk = 0; kk < 2; ++kk)
          acc[half * 2 + m][n] = MFMA16(af[m][kk], bfr[n][kk], acc[half * 2 + m][n]);
    __builtin_amdgcn_s_setprio(0);
  };

  for (int t = 0; t < NT; ++t) {
    const int cur = t & 1;
    const short* Ab = &As[cur][0];
    const short* Bb = &Bs[cur][0];

    // phase 0: stage next tile, mf-half 0 (B loaded once, reused in half 1)
    if (t + 1 < NT) stage(cur ^ 1, t + 1);
    ldB(Bb); ldA(Ab, 0); mma(0);
    asm volatile("s_barrier" ::: "memory");
    // phase 1: mf-half 1
    ldA(Ab, 1); mma(1);
    asm volatile("s_waitcnt vmcnt(0)" ::: "memory");    // next-tile DMA landed
    asm volatile("s_waitcnt lgkmcnt(0)" ::: "memory");  // my reads of slot cur done
    asm volatile("s_barrier" ::: "memory");             // release slot cur
  }

#pragma unroll
  for (int i = 0; i < 4; ++i)
#pragma unroll
    for (int j = 0; j < 3; ++j)
#pragma unroll
      for (int r = 0; r < 4; ++r) {
        long row = tileM + wm + i * 16 + quad * 4 + r;
        long col = tileN + wn + j * 16 + l15;
        Ccat[row * CSTR + col] = f2bf(acc[i][j][r]);
      }
}

// ---------------- 128x128 GEMM (output projection): 512 blocks = 2/CU ----------
// Cf[4096,2048] = A[4096,2048] * Wo[2048,2048]^T, fp32 epilogue. Same protocol.
// Per wave 64x32 = 4x2 frags (32 acc VGPR). LDS 64 KiB -> 2 blocks/CU.
__global__ __launch_bounds__(512, 4) void gemm_out(
    const short* __restrict__ A, const short* __restrict__ Bm,
    float* __restrict__ Cf)
{
  __shared__ __align__(16) short As[2][128 * 64];   // 32 KiB
  __shared__ __align__(16) short Bs[2][128 * 64];   // 32 KiB

  const int N = 2048, K = 2048;
  const long tileM = (long)blockIdx.y * 128;
  const long tileN = (long)blockIdx.x * 128;

  const int tid  = threadIdx.x;
  const int lane = tid & 63;
  const int quad = lane >> 4;
  const int l15  = lane & 15;
  const int wave = tid >> 6;
  const int wm   = (wave >> 2) * 64;
  const int wn   = (wave & 3) * 32;
  const int xsw  = l15 & 7;

  f32x4 acc[4][2];
#pragma unroll
  for (int i = 0; i < 4; ++i)
#pragma unroll
    for (int j = 0; j < 2; ++j) acc[i][j] = f32x4{0.f, 0.f, 0.f, 0.f};

  const int cS = (tid & 7) ^ ((tid >> 3) & 7);
  const short* gA[2]; const short* gB[2];
#pragma unroll
  for (int p = 0; p < 2; ++p) {
    gA[p] = A  + (tileM + (tid >> 3) + 64 * p) * K + cS * 8;
    gB[p] = Bm + (tileN + (tid >> 3) + 64 * p) * K + cS * 8;
  }

  auto stage = [&](int buf, int t) {
    const long ko = (long)t * 64;
    short* la = &As[buf][0];
    short* lb = &Bs[buf][0];
#pragma unroll
    for (int p = 0; p < 2; ++p) {
      gload_lds16(gA[p] + ko, la + (tid + p * 512) * 8);
      gload_lds16(gB[p] + ko, lb + (tid + p * 512) * 8);
    }
  };

  const int NT = K / 64;
  stage(0, 0);
  asm volatile("s_waitcnt vmcnt(0)" ::: "memory");
  asm volatile("s_barrier" ::: "memory");

  bf16x8 af[2][2], bfr[2][2];

  auto ldA = [&](const short* Ab, int half) {
#pragma unroll
    for (int m = 0; m < 2; ++m) {
      const int r = wm + (half * 2 + m) * 16 + l15;
#pragma unroll
      for (int kk = 0; kk < 2; ++kk)
        af[m][kk] = *(const bf16x8*)&Ab[r * 64 + (((kk * 4 + quad) ^ xsw) << 3)];
    }
  };
  auto ldB = [&](const short* Bb) {
#pragma unroll
    for (int n = 0; n < 2; ++n) {
      const int r = wn + n * 16 + l15;
#pragma unroll
      for (int kk = 0; kk < 2; ++kk)
        bfr[n][kk] = *(const bf16x8*)&Bb[r * 64 + (((kk * 4 + quad) ^ xsw) << 3)];
    }
  };
  auto mma = [&](int half) {
    __builtin_amdgcn_s_setprio(1);
#pragma unroll
    for (int m = 0; m < 2; ++m)
#pragma unroll
      for (int n = 0; n < 2; ++n)
#pragma unroll
        for (int kk = 0; kk < 2; ++kk)
          acc[half * 2 + m][n] = MFMA16(af[m][kk], bfr[n][kk], acc[half * 2 + m][n]);
    __builtin_amdgcn_s_setprio(0);
  };

  for (int t = 0; t < NT; ++t) {
    const int cur = t & 1;
    const short* Ab = &As[cur][0];
    const short* Bb = &Bs[cur][0];

    if (t + 1 < NT) stage(cur ^ 1, t + 1);
    ldB(Bb); ldA(Ab, 0); mma(0);
    asm volatile("s_barrier" ::: "memory");
    ldA(Ab, 1); mma(1);
    asm volatile("s_waitcnt vmcnt(0)" ::: "memory");
    asm volatile("s_waitcnt lgkmcnt(0)" ::: "memory");
    asm volatile("s_barrier" ::: "memory");
  }

#pragma unroll
  for (int i = 0; i < 4; ++i)
#pragma unroll
    for (int j = 0; j < 2; ++j)
#pragma unroll
      for (int r = 0; r < 4; ++r) {
        long row = tileM + wm + i * 16 + quad * 4 + r;
        long col = tileN + wn + j * 16 + l15;
        Cf[row * N + col] = acc[i][j][r];
      }
}

// ---------------- fused RoPE (Q,K in-place in Ccat) + V transpose ---------------
// Q = Ccat cols 0..2047, K = cols 2048..2559, V = cols 2560..3071 (stride 3072).
// Vectorized x8; math identical to previous (bit-identical output).
// Q scaled by (1/8)*log2(e); V^T written slot-permuted for the attn PV A-frag.
#define ROPE_BLOCKS 2560          // Q: 2048 blocks, K: 512 blocks (x8 vectorized)
__global__ void rope_vtrans_kernel(short* __restrict__ Ccat, short* __restrict__ Vt) {
  __shared__ short tile[64][65];
  if (blockIdx.x < ROPE_BLOCKS) {
    const int QT = (B_ * S_) * NH_ * 4;  // 524288 Q threads (4 groups of 8 per head)
    int t = blockIdx.x * blockDim.x + threadIdx.x;
    long base; int g; float scale; int row;
    if (t < QT) {
      row = t >> 7; int rem = t & 127, head = rem >> 2; g = rem & 3;
      base = (long)row * CSTR + head * HD_;
      scale = 0.125f * 1.44269504f;
    } else {
      int t2 = t - QT;
      row = t2 >> 5; int rem = t2 & 31, head = rem >> 2; g = rem & 3;
      base = (long)row * CSTR + 2048 + head * HD_;
      scale = 1.0f;
    }
    const int s = row & (S_ - 1);
    const int i0 = g * 8;
    union V8 { bf16x8 v; short e[8]; };
    V8 x0, x1, y0, y1;
    x0.v = *(const bf16x8*)&Ccat[base + i0];
    x1.v = *(const bf16x8*)&Ccat[base + i0 + 32];
#pragma unroll
    for (int j = 0; j < 8; ++j) {
      const int i = i0 + j;
      float invr = exp2f((float)i * -0.41524101f) * 0.15915494309f;
      float rev = (float)s * invr;
      rev -= floorf(rev);
      float ar = rev * 6.28318530718f;
      float c = __cosf(ar), sn = __sinf(ar);
      float a = bf2f(x0.e[j]);
      float b = bf2f(x1.e[j]);
      y0.e[j] = f2bf((a * c - b * sn) * scale);
      y1.e[j] = f2bf((b * c + a * sn) * scale);
    }
    *(bf16x8*)&Ccat[base + i0]      = y0.v;
    *(bf16x8*)&Ccat[base + i0 + 32] = y1.v;
  } else {
    int blk = blockIdx.x - ROPE_BLOCKS;
    int s0 = (blk & 31) * 64;
    int h  = (blk >> 5) & 7;
    int b  = blk >> 8;
    int tid = threadIdx.x;
#pragma unroll
    for (int it = 0; it < 16; ++it) {
      int idx = tid + it * 256;
      int r = idx >> 6, c = idx & 63;
      tile[r][c] = Ccat[((long)(b * S_ + s0 + r)) * CSTR + 2560 + h * HD_ + c];
    }
    __syncthreads();
#pragma unroll
    for (int it = 0; it < 16; ++it) {
      int idx = tid + it * 256;
      int d = idx >> 6, s = idx & 63;
      int slot = (s & 0x20) | (((s >> 2) & 3) << 3) | (((s >> 4) & 1) << 2) | (s & 3);
      Vt[((long)((b * NKV_ + h) * HD_ + d)) * S_ + s0 + slot] = tile[s][d];
    }
  }
}

// ---------------- Flash attention (causal, GQA), transposed-score form ----------
// 128 q-rows per block (two 16-row fragments per wave). Grid (16, 32) x2
// launches (bh halves). Q/K read from Ccat (stride 3072); V^T from Vt.
// 3-buffer, 2-deep prefetch with counted vmcnt(4); one barrier per iteration.
__global__ __launch_bounds__(256, 3) void attn_kernel(
    const short* __restrict__ Ccat, const short* __restrict__ Vt,
    short* __restrict__ O, int bh0)
{
  const int qt = 15 - (int)blockIdx.x;   // 128-row q-tile, long blocks first
  const int kmax = 2 * qt + 1;           // last 64-key tile index
  const int bh = blockIdx.y + bh0;
  const int b = bh >> 5, h = bh & 31, hkv = h >> 2;
  const int tid = threadIdx.x, lane = tid & 63, w = tid >> 6;
  const int quad = lane >> 4, l15 = lane & 15;

  __shared__ __align__(16) short Ks[3][64 * 64];   // [key][feature], chunk-swizzled
  __shared__ __align__(16) short Vs[3][64 * 64];   // [d][slot], chunk-swizzled

  const int qbase = qt * 128 + w * 16;   // frag0 rows qbase+l15, frag1 +64
  const short* qb0 = Ccat + ((long)(b * S_ + qbase + l15)) * CSTR + h * HD_;
  const short* qb1 = qb0 + 64L * CSTR;
  const bf16x8 aq00 = *(const bf16x8*)(qb0 + quad * 8);
  const bf16x8 aq01 = *(const bf16x8*)(qb0 + 32 + quad * 8);
  const bf16x8 aq10 = *(const bf16x8*)(qb1 + quad * 8);
  const bf16x8 aq11 = *(const bf16x8*)(qb1 + 32 + quad * 8);

  f32x4 o0[4], o1[4];
#pragma unroll
  for (int i = 0; i < 4; ++i) {
    o0[i] = f32x4{0.f, 0.f, 0.f, 0.f};
    o1[i] = f32x4{0.f, 0.f, 0.f, 0.f};
  }
  f32x4 li0 = f32x4{0.f, 0.f, 0.f, 0.f};
  f32x4 li1 = f32x4{0.f, 0.f, 0.f, 0.f};

  const short* kg = Ccat + ((long)(b * S_)) * CSTR + 2048 + hkv * HD_;
  const short* vg = Vt + ((long)((b * NKV_ + hkv) * HD_)) * S_;

  const int rK = tid >> 3;                       // 0..31 (second half adds 32)
  const int cC = (tid & 7) ^ (rK & 7);           // +32 preserves &7
  const short* kSrc = kg + (long)rK * CSTR + cC * 8;
  const short* vSrc = vg + (long)rK * S_ + cC * 8;
  short* kDst = &Ks[0][tid * 8];
  short* vDst = &Vs[0][tid * 8];

  auto stage = [&](int buf, int kb) {
    const long ko = (long)kb * 64 * CSTR;
    const long vo = (long)kb * 64;
    const int bo = buf * 4096;
    gload_lds16(kSrc + ko,              kDst + bo);
    gload_lds16(kSrc + ko + 32L * CSTR, kDst + bo + 2048);
    gload_lds16(vSrc + vo,              vDst + bo);
    gload_lds16(vSrc + vo + 32L * S_,   vDst + bo + 2048);
  };

  stage(0, 0);
  if (kmax >= 1) stage(1, 1);

  const int thr = w * 16 + l15;   // diagonal mask threshold (key offset vs row)
  union U8 { uint32_t u[4]; bf16x8 v; };

  int cur = 0;
  for (int kb = 0; kb <= kmax; ++kb) {
    if (kb < kmax) asm volatile("s_waitcnt vmcnt(4)" ::: "memory");
    else           asm volatile("s_waitcnt vmcnt(0)" ::: "memory");
    asm volatile("s_barrier" ::: "memory");      // buf[cur] staged, prev reads done
    if (kb + 2 <= kmax) {
      int nb = cur + 2; if (nb >= 3) nb -= 3;
      stage(nb, kb + 2);                         // 2-deep prefetch
    }
    const short* Kb = &Ks[cur][0];
    const short* Vb = &Vs[cur][0];
    const bool doF0 = (kb != kmax);              // frag0 fully masked at kmax

    // ---- Sc^T = K·Q^T (K-frags shared across both q-fragments) ----
    f32x4 s0[4], s1[4];
    __builtin_amdgcn_s_setprio(1);
#pragma unroll
    for (int nt = 0; nt < 4; ++nt) {
      const int r = nt * 16 + l15;
      bf16x8 k0 = *(const bf16x8*)&Kb[(r * 8 + ((quad)     ^ (r & 7))) * 8];
      bf16x8 k1 = *(const bf16x8*)&Kb[(r * 8 + ((quad + 4) ^ (r & 7))) * 8];
      f32x4 t = f32x4{0.f, 0.f, 0.f, 0.f};
      t = MFMA16(k0, aq10, t);
      t = MFMA16(k1, aq11, t);
      s1[nt] = t;
      if (doF0) {
        f32x4 u = f32x4{0.f, 0.f, 0.f, 0.f};
        u = MFMA16(k0, aq00, u);
        u = MFMA16(k1, aq01, u);
        s0[nt] = u;
      }
    }
    __builtin_amdgcn_s_setprio(0);

    // ---- causal mask (diagonal tiles only) ----
    if (kb == kmax) {            // frag1 diagonal
#pragma unroll
      for (int nt = 0; nt < 4; ++nt) {
        const int base = nt * 16 + quad * 4;
#pragma unroll
        for (int rr = 0; rr < 4; ++rr)
          if (base + rr > thr) s1[nt][rr] = -1e30f;
      }
    }
    if (doF0 && kb == kmax - 1) {   // frag0 diagonal
#pragma unroll
      for (int nt = 0; nt < 4; ++nt) {
        const int base = nt * 16 + quad * 4;
#pragma unroll
        for (int rr = 0; rr < 4; ++rr)
          if (base + rr > thr) s0[nt][rr] = -1e30f;
      }
    }

    // ---- exp2 + pack to P^T B-fragments (registers only) ----
    U8 p0[2], p1[2];
#pragma unroll
    for (int kt = 0; kt < 2; ++kt) {
      float e0 = fast_exp2(s1[2 * kt][0]),     e1 = fast_exp2(s1[2 * kt][1]);
      float e2 = fast_exp2(s1[2 * kt][2]),     e3 = fast_exp2(s1[2 * kt][3]);
      float e4 = fast_exp2(s1[2 * kt + 1][0]), e5 = fast_exp2(s1[2 * kt + 1][1]);
      float e6 = fast_exp2(s1[2 * kt + 1][2]), e7 = fast_exp2(s1[2 * kt + 1][3]);
      p1[kt].u[0] = f2bf_pk(e0, e1);
      p1[kt].u[1] = f2bf_pk(e2, e3);
      p1[kt].u[2] = f2bf_pk(e4, e5);
      p1[kt].u[3] = f2bf_pk(e6, e7);
      li1 += f32x4{e0, e1, e2, e3};
      li1 += f32x4{e4, e5, e6, e7};
    }
    if (doF0) {
#pragma unroll
      for (int kt = 0; kt < 2; ++kt) {
        float e0 = fast_exp2(s0[2 * kt][0]),     e1 = fast_exp2(s0[2 * kt][1]);
        float e2 = fast_exp2(s0[2 * kt][2]),     e3 = fast_exp2(s0[2 * kt][3]);
        float e4 = fast_exp2(s0[2 * kt + 1][0]), e5 = fast_exp2(s0[2 * kt + 1][1]);
        float e6 = fast_exp2(s0[2 * kt + 1][2]), e7 = fast_exp2(s0[2 * kt + 1][3]);
        p0[kt].u[0] = f2bf_pk(e0, e1);
        p0[kt].u[1] = f2bf_pk(e2, e3);
        p0[kt].u[2] = f2bf_pk(e4, e5);
        p0[kt].u[3] = f2bf_pk(e6, e7);
        li0 += f32x4{e0, e1, e2, e3};
        li0 += f32x4{e4, e5, e6, e7};
      }
    }

    // ---- O^T += V^T · P^T (V A-frags shared across both q-fragments) ----
    __builtin_amdgcn_s_setprio(1);
#pragma unroll
    for (int kt = 0; kt < 2; ++kt) {
      bf16x8 vf[4];
#pragma unroll
      for (int dt = 0; dt < 4; ++dt)
        vf[dt] = *(const bf16x8*)&Vb[(dt * 16 + l15) * 64 +
                                     (((kt * 4 + quad) ^ (l15 & 7)) << 3)];
#pragma unroll
      for (int dt = 0; dt < 4; ++dt)
        o1[dt] = MFMA16(vf[dt], p1[kt].v, o1[dt]);
      if (doF0) {
#pragma unroll
        for (int dt = 0; dt < 4; ++dt)
          o0[dt] = MFMA16(vf[dt], p0[kt].v, o0[dt]);
      }
    }
    __builtin_amdgcn_s_setprio(0);

    asm volatile("s_waitcnt lgkmcnt(0)" ::: "memory");   // all LDS reads serviced
    ++cur; if (cur == 3) cur = 0;
  }

  // ---- epilogue: O^T C-layout -> lane holds qrow=l15, d = dt*16+quad*4+r ----
  auto epi = [&](f32x4 (&o)[4], const f32x4& li4, int qrow0) {
    float l = (li4[0] + li4[1]) + (li4[2] + li4[3]);
    l += __shfl_xor(l, 16, 64);
    l += __shfl_xor(l, 32, 64);
    float invl = 1.0f / l;
    long orow = (long)(b * S_ + qrow0 + l15);
#pragma unroll
    for (int dt = 0; dt < 4; ++dt) {
      uint2 st;
      st.x = f2bf_pk(o[dt][0] * invl, o[dt][1] * invl);
      st.y = f2bf_pk(o[dt][2] * invl, o[dt][3] * invl);
      *(uint2*)&O[orow * (NH_ * HD_) + h * HD_ + dt * 16 + quad * 4] = st;
    }
  };
  epi(o1, li1, qbase + 64);
  epi(o0, li0, qbase);
}

// ---------------- launch -------------------------------------------------------
extern "C" void kernel_launch(void* const* d_in, const int* in_sizes, int n_in,
                              void* d_out, int out_size, void* d_ws, size_t ws_size,
                              hipStream_t stream) {
  const float* hs = (const float*)d_in[0];
  const float* Wq = (const float*)d_in[1];
  const float* Wk = (const float*)d_in[2];
  const float* Wv = (const float*)d_in[3];
  const float* Wo = (const float*)d_in[4];
  float* out = (float*)d_out;

  char* p = (char*)d_ws;
  auto carve = [&](size_t elems) { short* r = (short*)p; p += elems * 2; return r; };
  short* Xb   = carve(8388608);    // hidden bf16 [4096,2048]
  short* Wcat = carve(6291456);    // [Wq;Wk;Wv] rows -> [3072,2048]
  short* Wob  = carve(4194304);
  short* Ccat = carve(12582912);   // QKV-cat [4096,3072]
  short* Vtt  = carve(2097152);    // V^T [B,KV,HD,S] (slot-permuted)
  short* Om   = carve(8388608);    // attn out [4096,2048]

  short* Wqb = Wcat;               // rows 0..2047
  short* Wkb = Wcat + 4194304;     // rows 2048..2559
  short* Wvb = Wcat + 5242880;     // rows 2560..3071

  Cvt5Args ca{hs, Wq, Wk, Wv, Wo, Xb, Wqb, Wkb, Wvb, Wob};
  cvt5_kernel<<<CV4 / 256, 256, 0, stream>>>(ca);

  // QKV-cat projection: 128x192 tiles, grid 16x32 = 512 blocks = 2/CU
  gemm_qkvcat<<<dim3(16, 32), 512, 0, stream>>>(Xb, Wcat, Ccat);

  rope_vtrans_kernel<<<ROPE_BLOCKS + 512, 256, 0, stream>>>(Ccat, Vtt);

  // attention split into two independent bh halves
  attn_kernel<<<dim3(16, 32, 1), 256, 0, stream>>>(Ccat, Vtt, Om, 0);
  attn_kernel<<<dim3(16, 32, 1), 256, 0, stream>>>(Ccat, Vtt, Om, 32);

  // Output projection: 128x128 tiles, grid 16x32 = 512 blocks = 2/CU
  gemm_out<<<dim3(16, 32), 512, 0, stream>>>(Om, Wob, out);
}

// Round 9
// 298.568 us; speedup vs baseline: 1.1230x; 1.0113x over previous
//
#include <hip/hip_runtime.h>
#include <hip/hip_bf16.h>
#include <cstdint>
#include <cmath>

// Problem constants
#define B_   2
#define S_   2048
#define H_   2048
#define NH_  32
#define NKV_ 8
#define HD_  64
#define CSTR 3072   // row stride of the concatenated QKV output [4096, 3072]

using bf16x8 = __attribute__((ext_vector_type(8))) short;
using f32x4  = __attribute__((ext_vector_type(4))) float;

#define MFMA16(a, b, c) __builtin_amdgcn_mfma_f32_16x16x32_bf16((a), (b), (c), 0, 0, 0)

__device__ __forceinline__ short f2bf(float f) {   // round-nearest-even
  uint32_t u = __float_as_uint(f);
  uint32_t r = (u + 0x7fffu + ((u >> 16) & 1u)) >> 16;
  return (short)r;
}
__device__ __forceinline__ float bf2f(short s) {
  return __uint_as_float(((uint32_t)(uint16_t)s) << 16);
}
// packed 2xf32 -> 2xbf16 (hardware op when available)
__device__ __forceinline__ uint32_t f2bf_pk(float a, float b) {
#if __has_builtin(__builtin_amdgcn_cvt_pk_bf16_f32)
  auto r = __builtin_amdgcn_cvt_pk_bf16_f32(a, b);
  uint32_t u; __builtin_memcpy(&u, &r, sizeof(u));
  return u;
#else
  uint32_t ua = (__float_as_uint(a) + 0x8000u) >> 16;
  uint32_t ub = (__float_as_uint(b) + 0x8000u) >> 16;
  return ua | (ub << 16);
#endif
}
// raw v_exp_f32 (2^x)
__device__ __forceinline__ float fast_exp2(float x) {
#if __has_builtin(__builtin_amdgcn_exp2f)
  return __builtin_amdgcn_exp2f(x);
#else
  return exp2f(x);
#endif
}

__device__ __forceinline__ void gload_lds16(const void* g, void* l) {
  __builtin_amdgcn_global_load_lds((const __attribute__((address_space(1))) void*)g,
                                   (__attribute__((address_space(3))) void*)l, 16, 0, 0);
}

// ---------------- fused fp32 -> bf16 convert for all 5 tensors ------------------
struct Cvt5Args {
  const float *s0, *s1, *s2, *s3, *s4;
  short *d0, *d1, *d2, *d3, *d4;
};
#define CV0 2097152             // hs      (float4 units)
#define CV1 (CV0 + 1048576)     // Wq
#define CV2 (CV1 + 262144)      // Wk
#define CV3 (CV2 + 262144)      // Wv
#define CV4 (CV3 + 1048576)     // Wo -> total 4718592
__global__ void cvt5_kernel(Cvt5Args a) {
  int i = blockIdx.x * blockDim.x + threadIdx.x;
  const float* s; short* d; int off;
  if      (i < CV0) { s = a.s0; d = a.d0; off = i; }
  else if (i < CV1) { s = a.s1; d = a.d1; off = i - CV0; }
  else if (i < CV2) { s = a.s2; d = a.d2; off = i - CV1; }
  else if (i < CV3) { s = a.s3; d = a.d3; off = i - CV2; }
  else              { s = a.s4; d = a.d4; off = i - CV3; }
  const float4 v = ((const float4*)s)[off];
  uint2 o;
  o.x = (uint32_t)(uint16_t)f2bf(v.x) | ((uint32_t)(uint16_t)f2bf(v.y) << 16);
  o.y = (uint32_t)(uint16_t)f2bf(v.z) | ((uint32_t)(uint16_t)f2bf(v.w) << 16);
  ((uint2*)d)[off] = o;
}

// ---------------- 128x192 QKV-cat GEMM: grid 16x32 = 512 blocks = 2/CU ---------
// Ccat[4096,3072] = X[4096,2048] * Wcat[3072,2048]^T. BK=64, 512 threads =
// 8 waves (2M x 4N); per wave 64x48 output = 4x3 16x16 frags (48 acc VGPR).
// LDS = A 2x16K + B 2x24K = EXACTLY 80 KiB -> 2 blocks/CU (4 waves/SIMD).
// R7-verified: 52 us, MfmaUtil ~41, 990 TF. Cross-block overlap (m114) covers
// the end-of-tile vmcnt(0) drain. Protocol & XOR swizzle unchanged.
__global__ __launch_bounds__(512, 4) void gemm_qkvcat(
    const short* __restrict__ A, const short* __restrict__ Bcat,
    short* __restrict__ Ccat)
{
  __shared__ __align__(16) short As[2][128 * 64];   // 32 KiB
  __shared__ __align__(16) short Bs[2][192 * 64];   // 48 KiB

  const long tileM = (long)blockIdx.y * 128;
  const long tileN = (long)blockIdx.x * 192;
  const int  K = 2048;

  const int tid  = threadIdx.x;
  const int lane = tid & 63;
  const int quad = lane >> 4;
  const int l15  = lane & 15;
  const int wave = tid >> 6;
  const int wm   = (wave >> 2) * 64;      // 0 / 64
  const int wn   = (wave & 3) * 48;       // 0..144 (multiple of 16)
  const int xsw  = l15 & 7;

  f32x4 acc[4][3];
#pragma unroll
  for (int i = 0; i < 4; ++i)
#pragma unroll
    for (int j = 0; j < 3; ++j) acc[i][j] = f32x4{0.f, 0.f, 0.f, 0.f};

  // Staging: thread c = tid + 512p covers row c>>3, LDS chunk c&7 (linear dest).
  // Global source chunk = swizzle inverse. A: 2 passes (128 rows), B: 3 (192).
  const int cS = (tid & 7) ^ ((tid >> 3) & 7);
  const short* gA[2]; const short* gB[3];
#pragma unroll
  for (int p = 0; p < 2; ++p)
    gA[p] = A + (tileM + (tid >> 3) + 64 * p) * K + cS * 8;
#pragma unroll
  for (int p = 0; p < 3; ++p)
    gB[p] = Bcat + (tileN + (tid >> 3) + 64 * p) * K + cS * 8;

  auto stage = [&](int buf, int t) {
    const long ko = (long)t * 64;
    short* la = &As[buf][0];
    short* lb = &Bs[buf][0];
#pragma unroll
    for (int p = 0; p < 2; ++p)
      gload_lds16(gA[p] + ko, la + (tid + p * 512) * 8);
#pragma unroll
    for (int p = 0; p < 3; ++p)
      gload_lds16(gB[p] + ko, lb + (tid + p * 512) * 8);
  };

  const int NT = K / 64;                       // 32
  stage(0, 0);
  asm volatile("s_waitcnt vmcnt(0)" ::: "memory");
  asm volatile("s_barrier" ::: "memory");

  bf16x8 af[2][2], bfr[3][2];

  auto ldA = [&](const short* Ab, int half) {
#pragma unroll
    for (int m = 0; m < 2; ++m) {
      const int r = wm + (half * 2 + m) * 16 + l15;
#pragma unroll
      for (int kk = 0; kk < 2; ++kk)
        af[m][kk] = *(const bf16x8*)&Ab[r * 64 + (((kk * 4 + quad) ^ xsw) << 3)];
    }
  };
  auto ldB = [&](const short* Bb) {
#pragma unroll
    for (int n = 0; n < 3; ++n) {
      const int r = wn + n * 16 + l15;
#pragma unroll
      for (int kk = 0; kk < 2; ++kk)
        bfr[n][kk] = *(const bf16x8*)&Bb[r * 64 + (((kk * 4 + quad) ^ xsw) << 3)];
    }
  };
  auto mma = [&](int half) {
    __builtin_amdgcn_s_setprio(1);
#pragma unroll
    for (int m = 0; m < 2; ++m)
#pragma unroll
      for (int n = 0; n < 3; ++n)
#pragma unroll
        for (int kk = 0; kk < 2; ++kk)
          acc[half * 2 + m][n] = MFMA16(af[m][kk], bfr[n][kk], acc[half * 2 + m][n]);
    __builtin_amdgcn_s_setprio(0);
  };

  for (int t = 0; t < NT; ++t) {
    const int cur = t & 1;
    const short* Ab = &As[cur][0];
    const short* Bb = &Bs[cur][0];

    // phase 0: stage next tile, mf-half 0 (B loaded once, reused in half 1)
    if (t + 1 < NT) stage(cur ^ 1, t + 1);
    ldB(Bb); ldA(Ab, 0); mma(0);
    asm volatile("s_barrier" ::: "memory");
    // phase 1: mf-half 1
    ldA(Ab, 1); mma(1);
    asm volatile("s_waitcnt vmcnt(0)" ::: "memory");    // next-tile DMA landed
    asm volatile("s_waitcnt lgkmcnt(0)" ::: "memory");  // my reads of slot cur done
    asm volatile("s_barrier" ::: "memory");             // release slot cur
  }

#pragma unroll
  for (int i = 0; i < 4; ++i)
#pragma unroll
    for (int j = 0; j < 3; ++j)
#pragma unroll
      for (int r = 0; r < 4; ++r) {
        long row = tileM + wm + i * 16 + quad * 4 + r;
        long col = tileN + wn + j * 16 + l15;
        Ccat[row * CSTR + col] = f2bf(acc[i][j][r]);
      }
}

// ---------------- 128x128 GEMM (output projection): 512 blocks = 2/CU ----------
// Cf[4096,2048] = A[4096,2048] * Wo[2048,2048]^T, fp32 epilogue. Same protocol.
// Per wave 64x32 = 4x2 frags (32 acc VGPR). LDS 64 KiB -> 2 blocks/CU.
__global__ __launch_bounds__(512, 4) void gemm_out(
    const short* __restrict__ A, const short* __restrict__ Bm,
    float* __restrict__ Cf)
{
  __shared__ __align__(16) short As[2][128 * 64];   // 32 KiB
  __shared__ __align__(16) short Bs[2][128 * 64];   // 32 KiB

  const int N = 2048, K = 2048;
  const long tileM = (long)blockIdx.y * 128;
  const long tileN = (long)blockIdx.x * 128;

  const int tid  = threadIdx.x;
  const int lane = tid & 63;
  const int quad = lane >> 4;
  const int l15  = lane & 15;
  const int wave = tid >> 6;
  const int wm   = (wave >> 2) * 64;
  const int wn   = (wave & 3) * 32;
  const int xsw  = l15 & 7;

  f32x4 acc[4][2];
#pragma unroll
  for (int i = 0; i < 4; ++i)
#pragma unroll
    for (int j = 0; j < 2; ++j) acc[i][j] = f32x4{0.f, 0.f, 0.f, 0.f};

  const int cS = (tid & 7) ^ ((tid >> 3) & 7);
  const short* gA[2]; const short* gB[2];
#pragma unroll
  for (int p = 0; p < 2; ++p) {
    gA[p] = A  + (tileM + (tid >> 3) + 64 * p) * K + cS * 8;
    gB[p] = Bm + (tileN + (tid >> 3) + 64 * p) * K + cS * 8;
  }

  auto stage = [&](int buf, int t) {
    const long ko = (long)t * 64;
    short* la = &As[buf][0];
    short* lb = &Bs[buf][0];
#pragma unroll
    for (int p = 0; p < 2; ++p) {
      gload_lds16(gA[p] + ko, la + (tid + p * 512) * 8);
      gload_lds16(gB[p] + ko, lb + (tid + p * 512) * 8);
    }
  };

  const int NT = K / 64;
  stage(0, 0);
  asm volatile("s_waitcnt vmcnt(0)" ::: "memory");
  asm volatile("s_barrier" ::: "memory");

  bf16x8 af[2][2], bfr[2][2];

  auto ldA = [&](const short* Ab, int half) {
#pragma unroll
    for (int m = 0; m < 2; ++m) {
      const int r = wm + (half * 2 + m) * 16 + l15;
#pragma unroll
      for (int kk = 0; kk < 2; ++kk)
        af[m][kk] = *(const bf16x8*)&Ab[r * 64 + (((kk * 4 + quad) ^ xsw) << 3)];
    }
  };
  auto ldB = [&](const short* Bb) {
#pragma unroll
    for (int n = 0; n < 2; ++n) {
      const int r = wn + n * 16 + l15;
#pragma unroll
      for (int kk = 0; kk < 2; ++kk)
        bfr[n][kk] = *(const bf16x8*)&Bb[r * 64 + (((kk * 4 + quad) ^ xsw) << 3)];
    }
  };
  auto mma = [&](int half) {
    __builtin_amdgcn_s_setprio(1);
#pragma unroll
    for (int m = 0; m < 2; ++m)
#pragma unroll
      for (int n = 0; n < 2; ++n)
#pragma unroll
        for (int kk = 0; kk < 2; ++kk)
          acc[half * 2 + m][n] = MFMA16(af[m][kk], bfr[n][kk], acc[half * 2 + m][n]);
    __builtin_amdgcn_s_setprio(0);
  };

  for (int t = 0; t < NT; ++t) {
    const int cur = t & 1;
    const short* Ab = &As[cur][0];
    const short* Bb = &Bs[cur][0];

    if (t + 1 < NT) stage(cur ^ 1, t + 1);
    ldB(Bb); ldA(Ab, 0); mma(0);
    asm volatile("s_barrier" ::: "memory");
    ldA(Ab, 1); mma(1);
    asm volatile("s_waitcnt vmcnt(0)" ::: "memory");
    asm volatile("s_waitcnt lgkmcnt(0)" ::: "memory");
    asm volatile("s_barrier" ::: "memory");
  }

#pragma unroll
  for (int i = 0; i < 4; ++i)
#pragma unroll
    for (int j = 0; j < 2; ++j)
#pragma unroll
      for (int r = 0; r < 4; ++r) {
        long row = tileM + wm + i * 16 + quad * 4 + r;
        long col = tileN + wn + j * 16 + l15;
        Cf[row * N + col] = acc[i][j][r];
      }
}

// ---------------- fused RoPE (Q,K in-place in Ccat) + V transpose ---------------
// Q = Ccat cols 0..2047, K = cols 2048..2559, V = cols 2560..3071 (stride 3072).
// Vectorized x8; math identical to previous (bit-identical output).
// Q scaled by (1/8)*log2(e); V^T written slot-permuted for the attn PV A-frag.
#define ROPE_BLOCKS 2560          // Q: 2048 blocks, K: 512 blocks (x8 vectorized)
__global__ void rope_vtrans_kernel(short* __restrict__ Ccat, short* __restrict__ Vt) {
  __shared__ short tile[64][65];
  if (blockIdx.x < ROPE_BLOCKS) {
    const int QT = (B_ * S_) * NH_ * 4;  // 524288 Q threads (4 groups of 8 per head)
    int t = blockIdx.x * blockDim.x + threadIdx.x;
    long base; int g; float scale; int row;
    if (t < QT) {
      row = t >> 7; int rem = t & 127, head = rem >> 2; g = rem & 3;
      base = (long)row * CSTR + head * HD_;
      scale = 0.125f * 1.44269504f;
    } else {
      int t2 = t - QT;
      row = t2 >> 5; int rem = t2 & 31, head = rem >> 2; g = rem & 3;
      base = (long)row * CSTR + 2048 + head * HD_;
      scale = 1.0f;
    }
    const int s = row & (S_ - 1);
    const int i0 = g * 8;
    union V8 { bf16x8 v; short e[8]; };
    V8 x0, x1, y0, y1;
    x0.v = *(const bf16x8*)&Ccat[base + i0];
    x1.v = *(const bf16x8*)&Ccat[base + i0 + 32];
#pragma unroll
    for (int j = 0; j < 8; ++j) {
      const int i = i0 + j;
      float invr = exp2f((float)i * -0.41524101f) * 0.15915494309f;
      float rev = (float)s * invr;
      rev -= floorf(rev);
      float ar = rev * 6.28318530718f;
      float c = __cosf(ar), sn = __sinf(ar);
      float a = bf2f(x0.e[j]);
      float b = bf2f(x1.e[j]);
      y0.e[j] = f2bf((a * c - b * sn) * scale);
      y1.e[j] = f2bf((b * c + a * sn) * scale);
    }
    *(bf16x8*)&Ccat[base + i0]      = y0.v;
    *(bf16x8*)&Ccat[base + i0 + 32] = y1.v;
  } else {
    int blk = blockIdx.x - ROPE_BLOCKS;
    int s0 = (blk & 31) * 64;
    int h  = (blk >> 5) & 7;
    int b  = blk >> 8;
    int tid = threadIdx.x;
#pragma unroll
    for (int it = 0; it < 16; ++it) {
      int idx = tid + it * 256;
      int r = idx >> 6, c = idx & 63;
      tile[r][c] = Ccat[((long)(b * S_ + s0 + r)) * CSTR + 2560 + h * HD_ + c];
    }
    __syncthreads();
#pragma unroll
    for (int it = 0; it < 16; ++it) {
      int idx = tid + it * 256;
      int d = idx >> 6, s = idx & 63;
      int slot = (s & 0x20) | (((s >> 2) & 3) << 3) | (((s >> 4) & 1) << 2) | (s & 3);
      Vt[((long)((b * NKV_ + h) * HD_ + d)) * S_ + s0 + slot] = tile[s][d];
    }
  }
}

// ---------------- Flash attention (causal, GQA), transposed-score form ----------
// SINGLE launch, grid (16, 64) = 1024 blocks = 3 resident + 1 backfill per CU
// (R7 post-mortem: the bh-split halved per-dispatch parallelism and cost
// ~12 us -- 2x52 vs 92 merged -- plus one launch gap. Merged back.)
// 128 q-rows per block (two 16-row fragments per wave); LPT via qt = 15 - x.
// 3-buffer, 2-deep prefetch with counted vmcnt(4); one barrier per iteration.
__global__ __launch_bounds__(256, 3) void attn_kernel(
    const short* __restrict__ Ccat, const short* __restrict__ Vt,
    short* __restrict__ O)
{
  const int qt = 15 - (int)blockIdx.x;   // 128-row q-tile, long blocks first
  const int kmax = 2 * qt + 1;           // last 64-key tile index
  const int bh = blockIdx.y;
  const int b = bh >> 5, h = bh & 31, hkv = h >> 2;
  const int tid = threadIdx.x, lane = tid & 63, w = tid >> 6;
  const int quad = lane >> 4, l15 = lane & 15;

  __shared__ __align__(16) short Ks[3][64 * 64];   // [key][feature], chunk-swizzled
  __shared__ __align__(16) short Vs[3][64 * 64];   // [d][slot], chunk-swizzled

  const int qbase = qt * 128 + w * 16;   // frag0 rows qbase+l15, frag1 +64
  const short* qb0 = Ccat + ((long)(b * S_ + qbase + l15)) * CSTR + h * HD_;
  const short* qb1 = qb0 + 64L * CSTR;
  const bf16x8 aq00 = *(const bf16x8*)(qb0 + quad * 8);
  const bf16x8 aq01 = *(const bf16x8*)(qb0 + 32 + quad * 8);
  const bf16x8 aq10 = *(const bf16x8*)(qb1 + quad * 8);
  const bf16x8 aq11 = *(const bf16x8*)(qb1 + 32 + quad * 8);

  f32x4 o0[4], o1[4];
#pragma unroll
  for (int i = 0; i < 4; ++i) {
    o0[i] = f32x4{0.f, 0.f, 0.f, 0.f};
    o1[i] = f32x4{0.f, 0.f, 0.f, 0.f};
  }
  f32x4 li0 = f32x4{0.f, 0.f, 0.f, 0.f};
  f32x4 li1 = f32x4{0.f, 0.f, 0.f, 0.f};

  const short* kg = Ccat + ((long)(b * S_)) * CSTR + 2048 + hkv * HD_;
  const short* vg = Vt + ((long)((b * NKV_ + hkv) * HD_)) * S_;

  const int rK = tid >> 3;                       // 0..31 (second half adds 32)
  const int cC = (tid & 7) ^ (rK & 7);           // +32 preserves &7
  const short* kSrc = kg + (long)rK * CSTR + cC * 8;
  const short* vSrc = vg + (long)rK * S_ + cC * 8;
  short* kDst = &Ks[0][tid * 8];
  short* vDst = &Vs[0][tid * 8];

  auto stage = [&](int buf, int kb) {
    const long ko = (long)kb * 64 * CSTR;
    const long vo = (long)kb * 64;
    const int bo = buf * 4096;
    gload_lds16(kSrc + ko,              kDst + bo);
    gload_lds16(kSrc + ko + 32L * CSTR, kDst + bo + 2048);
    gload_lds16(vSrc + vo,              vDst + bo);
    gload_lds16(vSrc + vo + 32L * S_,   vDst + bo + 2048);
  };

  stage(0, 0);
  if (kmax >= 1) stage(1, 1);

  const int thr = w * 16 + l15;   // diagonal mask threshold (key offset vs row)
  union U8 { uint32_t u[4]; bf16x8 v; };

  int cur = 0;
  for (int kb = 0; kb <= kmax; ++kb) {
    if (kb < kmax) asm volatile("s_waitcnt vmcnt(4)" ::: "memory");
    else           asm volatile("s_waitcnt vmcnt(0)" ::: "memory");
    asm volatile("s_barrier" ::: "memory");      // buf[cur] staged, prev reads done
    if (kb + 2 <= kmax) {
      int nb = cur + 2; if (nb >= 3) nb -= 3;
      stage(nb, kb + 2);                         // 2-deep prefetch
    }
    const short* Kb = &Ks[cur][0];
    const short* Vb = &Vs[cur][0];
    const bool doF0 = (kb != kmax);              // frag0 fully masked at kmax

    // ---- Sc^T = K·Q^T (K-frags shared across both q-fragments) ----
    f32x4 s0[4], s1[4];
    __builtin_amdgcn_s_setprio(1);
#pragma unroll
    for (int nt = 0; nt < 4; ++nt) {
      const int r = nt * 16 + l15;
      bf16x8 k0 = *(const bf16x8*)&Kb[(r * 8 + ((quad)     ^ (r & 7))) * 8];
      bf16x8 k1 = *(const bf16x8*)&Kb[(r * 8 + ((quad + 4) ^ (r & 7))) * 8];
      f32x4 t = f32x4{0.f, 0.f, 0.f, 0.f};
      t = MFMA16(k0, aq10, t);
      t = MFMA16(k1, aq11, t);
      s1[nt] = t;
      if (doF0) {
        f32x4 u = f32x4{0.f, 0.f, 0.f, 0.f};
        u = MFMA16(k0, aq00, u);
        u = MFMA16(k1, aq01, u);
        s0[nt] = u;
      }
    }
    __builtin_amdgcn_s_setprio(0);

    // ---- causal mask (diagonal tiles only) ----
    if (kb == kmax) {            // frag1 diagonal
#pragma unroll
      for (int nt = 0; nt < 4; ++nt) {
        const int base = nt * 16 + quad * 4;
#pragma unroll
        for (int rr = 0; rr < 4; ++rr)
          if (base + rr > thr) s1[nt][rr] = -1e30f;
      }
    }
    if (doF0 && kb == kmax - 1) {   // frag0 diagonal
#pragma unroll
      for (int nt = 0; nt < 4; ++nt) {
        const int base = nt * 16 + quad * 4;
#pragma unroll
        for (int rr = 0; rr < 4; ++rr)
          if (base + rr > thr) s0[nt][rr] = -1e30f;
      }
    }

    // ---- exp2 + pack to P^T B-fragments (registers only) ----
    U8 p0[2], p1[2];
#pragma unroll
    for (int kt = 0; kt < 2; ++kt) {
      float e0 = fast_exp2(s1[2 * kt][0]),     e1 = fast_exp2(s1[2 * kt][1]);
      float e2 = fast_exp2(s1[2 * kt][2]),     e3 = fast_exp2(s1[2 * kt][3]);
      float e4 = fast_exp2(s1[2 * kt + 1][0]), e5 = fast_exp2(s1[2 * kt + 1][1]);
      float e6 = fast_exp2(s1[2 * kt + 1][2]), e7 = fast_exp2(s1[2 * kt + 1][3]);
      p1[kt].u[0] = f2bf_pk(e0, e1);
      p1[kt].u[1] = f2bf_pk(e2, e3);
      p1[kt].u[2] = f2bf_pk(e4, e5);
      p1[kt].u[3] = f2bf_pk(e6, e7);
      li1 += f32x4{e0, e1, e2, e3};
      li1 += f32x4{e4, e5, e6, e7};
    }
    if (doF0) {
#pragma unroll
      for (int kt = 0; kt < 2; ++kt) {
        float e0 = fast_exp2(s0[2 * kt][0]),     e1 = fast_exp2(s0[2 * kt][1]);
        float e2 = fast_exp2(s0[2 * kt][2]),     e3 = fast_exp2(s0[2 * kt][3]);
        float e4 = fast_exp2(s0[2 * kt + 1][0]), e5 = fast_exp2(s0[2 * kt + 1][1]);
        float e6 = fast_exp2(s0[2 * kt + 1][2]), e7 = fast_exp2(s0[2 * kt + 1][3]);
        p0[kt].u[0] = f2bf_pk(e0, e1);
        p0[kt].u[1] = f2bf_pk(e2, e3);
        p0[kt].u[2] = f2bf_pk(e4, e5);
        p0[kt].u[3] = f2bf_pk(e6, e7);
        li0 += f32x4{e0, e1, e2, e3};
        li0 += f32x4{e4, e5, e6, e7};
      }
    }

    // ---- O^T += V^T · P^T (V A-frags shared across both q-fragments) ----
    __builtin_amdgcn_s_setprio(1);
#pragma unroll
    for (int kt = 0; kt < 2; ++kt) {
      bf16x8 vf[4];
#pragma unroll
      for (int dt = 0; dt < 4; ++dt)
        vf[dt] = *(const bf16x8*)&Vb[(dt * 16 + l15) * 64 +
                                     (((kt * 4 + quad) ^ (l15 & 7)) << 3)];
#pragma unroll
      for (int dt = 0; dt < 4; ++dt)
        o1[dt] = MFMA16(vf[dt], p1[kt].v, o1[dt]);
      if (doF0) {
#pragma unroll
        for (int dt = 0; dt < 4; ++dt)
          o0[dt] = MFMA16(vf[dt], p0[kt].v, o0[dt]);
      }
    }
    __builtin_amdgcn_s_setprio(0);

    asm volatile("s_waitcnt lgkmcnt(0)" ::: "memory");   // all LDS reads serviced
    ++cur; if (cur == 3) cur = 0;
  }

  // ---- epilogue: O^T C-layout -> lane holds qrow=l15, d = dt*16+quad*4+r ----
  auto epi = [&](f32x4 (&o)[4], const f32x4& li4, int qrow0) {
    float l = (li4[0] + li4[1]) + (li4[2] + li4[3]);
    l += __shfl_xor(l, 16, 64);
    l += __shfl_xor(l, 32, 64);
    float invl = 1.0f / l;
    long orow = (long)(b * S_ + qrow0 + l15);
#pragma unroll
    for (int dt = 0; dt < 4; ++dt) {
      uint2 st;
      st.x = f2bf_pk(o[dt][0] * invl, o[dt][1] * invl);
      st.y = f2bf_pk(o[dt][2] * invl, o[dt][3] * invl);
      *(uint2*)&O[orow * (NH_ * HD_) + h * HD_ + dt * 16 + quad * 4] = st;
    }
  };
  epi(o1, li1, qbase + 64);
  epi(o0, li0, qbase);
}

// ---------------- launch -------------------------------------------------------
extern "C" void kernel_launch(void* const* d_in, const int* in_sizes, int n_in,
                              void* d_out, int out_size, void* d_ws, size_t ws_size,
                              hipStream_t stream) {
  const float* hs = (const float*)d_in[0];
  const float* Wq = (const float*)d_in[1];
  const float* Wk = (const float*)d_in[2];
  const float* Wv = (const float*)d_in[3];
  const float* Wo = (const float*)d_in[4];
  float* out = (float*)d_out;

  char* p = (char*)d_ws;
  auto carve = [&](size_t elems) { short* r = (short*)p; p += elems * 2; return r; };
  short* Xb   = carve(8388608);    // hidden bf16 [4096,2048]
  short* Wcat = carve(6291456);    // [Wq;Wk;Wv] rows -> [3072,2048]
  short* Wob  = carve(4194304);
  short* Ccat = carve(12582912);   // QKV-cat [4096,3072]
  short* Vtt  = carve(2097152);    // V^T [B,KV,HD,S] (slot-permuted)
  short* Om   = carve(8388608);    // attn out [4096,2048]

  short* Wqb = Wcat;               // rows 0..2047
  short* Wkb = Wcat + 4194304;     // rows 2048..2559
  short* Wvb = Wcat + 5242880;     // rows 2560..3071

  Cvt5Args ca{hs, Wq, Wk, Wv, Wo, Xb, Wqb, Wkb, Wvb, Wob};
  cvt5_kernel<<<CV4 / 256, 256, 0, stream>>>(ca);

  // QKV-cat projection: 128x192 tiles, grid 16x32 = 512 blocks = 2/CU
  gemm_qkvcat<<<dim3(16, 32), 512, 0, stream>>>(Xb, Wcat, Ccat);

  rope_vtrans_kernel<<<ROPE_BLOCKS + 512, 256, 0, stream>>>(Ccat, Vtt);

  // attention: single launch, grid (16,64) = 1024 blocks (3 resident + 1
  // backfill per CU; LPT ordering via qt = 15 - x)
  attn_kernel<<<dim3(16, 64, 1), 256, 0, stream>>>(Ccat, Vtt, Om);

  // Output projection: 128x128 tiles, grid 16x32 = 512 blocks = 2/CU
  gemm_out<<<dim3(16, 32), 512, 0, stream>>>(Om, Wob, out);
}

// Round 10
// 281.373 us; speedup vs baseline: 1.1916x; 1.0611x over previous
//
#include <hip/hip_runtime.h>
#include <hip/hip_bf16.h>
#include <cstdint>
#include <cmath>

// Problem constants
#define B_   2
#define S_   2048
#define H_   2048
#define NH_  32
#define NKV_ 8
#define HD_  64
#define CSTR 3072   // row stride of the concatenated QKV output [4096, 3072]

using bf16x8 = __attribute__((ext_vector_type(8))) short;
using f32x4  = __attribute__((ext_vector_type(4))) float;

#define MFMA16(a, b, c) __builtin_amdgcn_mfma_f32_16x16x32_bf16((a), (b), (c), 0, 0, 0)

__device__ __forceinline__ short f2bf(float f) {   // round-nearest-even
  uint32_t u = __float_as_uint(f);
  uint32_t r = (u + 0x7fffu + ((u >> 16) & 1u)) >> 16;
  return (short)r;
}
__device__ __forceinline__ float bf2f(short s) {
  return __uint_as_float(((uint32_t)(uint16_t)s) << 16);
}
// packed 2xf32 -> 2xbf16 (hardware op when available)
__device__ __forceinline__ uint32_t f2bf_pk(float a, float b) {
#if __has_builtin(__builtin_amdgcn_cvt_pk_bf16_f32)
  auto r = __builtin_amdgcn_cvt_pk_bf16_f32(a, b);
  uint32_t u; __builtin_memcpy(&u, &r, sizeof(u));
  return u;
#else
  uint32_t ua = (__float_as_uint(a) + 0x8000u) >> 16;
  uint32_t ub = (__float_as_uint(b) + 0x8000u) >> 16;
  return ua | (ub << 16);
#endif
}
// raw v_exp_f32 (2^x)
__device__ __forceinline__ float fast_exp2(float x) {
#if __has_builtin(__builtin_amdgcn_exp2f)
  return __builtin_amdgcn_exp2f(x);
#else
  return exp2f(x);
#endif
}

__device__ __forceinline__ void gload_lds16(const void* g, void* l) {
  __builtin_amdgcn_global_load_lds((const __attribute__((address_space(1))) void*)g,
                                   (__attribute__((address_space(3))) void*)l, 16, 0, 0);
}

// ---------------- fused fp32 -> bf16 convert for all 5 tensors ------------------
struct Cvt5Args {
  const float *s0, *s1, *s2, *s3, *s4;
  short *d0, *d1, *d2, *d3, *d4;
};
#define CV0 2097152             // hs      (float4 units)
#define CV1 (CV0 + 1048576)     // Wq
#define CV2 (CV1 + 262144)      // Wk
#define CV3 (CV2 + 262144)      // Wv
#define CV4 (CV3 + 1048576)     // Wo -> total 4718592
__global__ void cvt5_kernel(Cvt5Args a) {
  int i = blockIdx.x * blockDim.x + threadIdx.x;
  const float* s; short* d; int off;
  if      (i < CV0) { s = a.s0; d = a.d0; off = i; }
  else if (i < CV1) { s = a.s1; d = a.d1; off = i - CV0; }
  else if (i < CV2) { s = a.s2; d = a.d2; off = i - CV1; }
  else if (i < CV3) { s = a.s3; d = a.d3; off = i - CV2; }
  else              { s = a.s4; d = a.d4; off = i - CV3; }
  const float4 v = ((const float4*)s)[off];
  uint2 o;
  o.x = (uint32_t)(uint16_t)f2bf(v.x) | ((uint32_t)(uint16_t)f2bf(v.y) << 16);
  o.y = (uint32_t)(uint16_t)f2bf(v.z) | ((uint32_t)(uint16_t)f2bf(v.w) << 16);
  ((uint2*)d)[off] = o;
}

// ---------------- 128x192 QKV-cat GEMM: grid 16x32 = 512 blocks = 2/CU ---------
// Ccat[4096,3072] = X[4096,2048] * Wcat[3072,2048]^T. BK=64, 512 threads =
// 8 waves (2M x 4N); per wave 64x48 output = 4x3 16x16 frags (48 acc VGPR).
// LDS = A 2x16K + B 2x24K = EXACTLY 80 KiB -> 2 blocks/CU (4 waves/SIMD).
// R7-verified: 52 us, MfmaUtil ~41, 990 TF. Cross-block overlap (m114) covers
// the end-of-tile vmcnt(0) drain. Protocol & XOR swizzle unchanged.
__global__ __launch_bounds__(512, 4) void gemm_qkvcat(
    const short* __restrict__ A, const short* __restrict__ Bcat,
    short* __restrict__ Ccat)
{
  __shared__ __align__(16) short As[2][128 * 64];   // 32 KiB
  __shared__ __align__(16) short Bs[2][192 * 64];   // 48 KiB

  const long tileM = (long)blockIdx.y * 128;
  const long tileN = (long)blockIdx.x * 192;
  const int  K = 2048;

  const int tid  = threadIdx.x;
  const int lane = tid & 63;
  const int quad = lane >> 4;
  const int l15  = lane & 15;
  const int wave = tid >> 6;
  const int wm   = (wave >> 2) * 64;      // 0 / 64
  const int wn   = (wave & 3) * 48;       // 0..144 (multiple of 16)
  const int xsw  = l15 & 7;

  f32x4 acc[4][3];
#pragma unroll
  for (int i = 0; i < 4; ++i)
#pragma unroll
    for (int j = 0; j < 3; ++j) acc[i][j] = f32x4{0.f, 0.f, 0.f, 0.f};

  // Staging: thread c = tid + 512p covers row c>>3, LDS chunk c&7 (linear dest).
  // Global source chunk = swizzle inverse. A: 2 passes (128 rows), B: 3 (192).
  const int cS = (tid & 7) ^ ((tid >> 3) & 7);
  const short* gA[2]; const short* gB[3];
#pragma unroll
  for (int p = 0; p < 2; ++p)
    gA[p] = A + (tileM + (tid >> 3) + 64 * p) * K + cS * 8;
#pragma unroll
  for (int p = 0; p < 3; ++p)
    gB[p] = Bcat + (tileN + (tid >> 3) + 64 * p) * K + cS * 8;

  auto stage = [&](int buf, int t) {
    const long ko = (long)t * 64;
    short* la = &As[buf][0];
    short* lb = &Bs[buf][0];
#pragma unroll
    for (int p = 0; p < 2; ++p)
      gload_lds16(gA[p] + ko, la + (tid + p * 512) * 8);
#pragma unroll
    for (int p = 0; p < 3; ++p)
      gload_lds16(gB[p] + ko, lb + (tid + p * 512) * 8);
  };

  const int NT = K / 64;                       // 32
  stage(0, 0);
  asm volatile("s_waitcnt vmcnt(0)" ::: "memory");
  asm volatile("s_barrier" ::: "memory");

  bf16x8 af[2][2], bfr[3][2];

  auto ldA = [&](const short* Ab, int half) {
#pragma unroll
    for (int m = 0; m < 2; ++m) {
      const int r = wm + (half * 2 + m) * 16 + l15;
#pragma unroll
      for (int kk = 0; kk < 2; ++kk)
        af[m][kk] = *(const bf16x8*)&Ab[r * 64 + (((kk * 4 + quad) ^ xsw) << 3)];
    }
  };
  auto ldB = [&](const short* Bb) {
#pragma unroll
    for (int n = 0; n < 3; ++n) {
      const int r = wn + n * 16 + l15;
#pragma unroll
      for (int kk = 0; kk < 2; ++kk)
        bfr[n][kk] = *(const bf16x8*)&Bb[r * 64 + (((kk * 4 + quad) ^ xsw) << 3)];
    }
  };
  auto mma = [&](int half) {
    __builtin_amdgcn_s_setprio(1);
#pragma unroll
    for (int m = 0; m < 2; ++m)
#pragma unroll
      for (int n = 0; n < 3; ++n)
#pragma unroll
        for (int kk = 0; kk < 2; ++kk)
          acc[half * 2 + m][n] = MFMA16(af[m][kk], bfr[n][kk], acc[half * 2 + m][n]);
    __builtin_amdgcn_s_setprio(0);
  };

  for (int t = 0; t < NT; ++t) {
    const int cur = t & 1;
    const short* Ab = &As[cur][0];
    const short* Bb = &Bs[cur][0];

    // phase 0: stage next tile, mf-half 0 (B loaded once, reused in half 1)
    if (t + 1 < NT) stage(cur ^ 1, t + 1);
    ldB(Bb); ldA(Ab, 0); mma(0);
    asm volatile("s_barrier" ::: "memory");
    // phase 1: mf-half 1
    ldA(Ab, 1); mma(1);
    asm volatile("s_waitcnt vmcnt(0)" ::: "memory");    // next-tile DMA landed
    asm volatile("s_waitcnt lgkmcnt(0)" ::: "memory");  // my reads of slot cur done
    asm volatile("s_barrier" ::: "memory");             // release slot cur
  }

#pragma unroll
  for (int i = 0; i < 4; ++i)
#pragma unroll
    for (int j = 0; j < 3; ++j)
#pragma unroll
      for (int r = 0; r < 4; ++r) {
        long row = tileM + wm + i * 16 + quad * 4 + r;
        long col = tileN + wn + j * 16 + l15;
        Ccat[row * CSTR + col] = f2bf(acc[i][j][r]);
      }
}

// ---------------- 128x128 GEMM (output projection): 512 blocks = 2/CU ----------
// Cf[4096,2048] = A[4096,2048] * Wo[2048,2048]^T, fp32 epilogue. Same protocol.
// Per wave 64x32 = 4x2 frags (32 acc VGPR). LDS 64 KiB -> 2 blocks/CU.
__global__ __launch_bounds__(512, 4) void gemm_out(
    const short* __restrict__ A, const short* __restrict__ Bm,
    float* __restrict__ Cf)
{
  __shared__ __align__(16) short As[2][128 * 64];   // 32 KiB
  __shared__ __align__(16) short Bs[2][128 * 64];   // 32 KiB

  const int N = 2048, K = 2048;
  const long tileM = (long)blockIdx.y * 128;
  const long tileN = (long)blockIdx.x * 128;

  const int tid  = threadIdx.x;
  const int lane = tid & 63;
  const int quad = lane >> 4;
  const int l15  = lane & 15;
  const int wave = tid >> 6;
  const int wm   = (wave >> 2) * 64;
  const int wn   = (wave & 3) * 32;
  const int xsw  = l15 & 7;

  f32x4 acc[4][2];
#pragma unroll
  for (int i = 0; i < 4; ++i)
#pragma unroll
    for (int j = 0; j < 2; ++j) acc[i][j] = f32x4{0.f, 0.f, 0.f, 0.f};

  const int cS = (tid & 7) ^ ((tid >> 3) & 7);
  const short* gA[2]; const short* gB[2];
#pragma unroll
  for (int p = 0; p < 2; ++p) {
    gA[p] = A  + (tileM + (tid >> 3) + 64 * p) * K + cS * 8;
    gB[p] = Bm + (tileN + (tid >> 3) + 64 * p) * K + cS * 8;
  }

  auto stage = [&](int buf, int t) {
    const long ko = (long)t * 64;
    short* la = &As[buf][0];
    short* lb = &Bs[buf][0];
#pragma unroll
    for (int p = 0; p < 2; ++p) {
      gload_lds16(gA[p] + ko, la + (tid + p * 512) * 8);
      gload_lds16(gB[p] + ko, lb + (tid + p * 512) * 8);
    }
  };

  const int NT = K / 64;
  stage(0, 0);
  asm volatile("s_waitcnt vmcnt(0)" ::: "memory");
  asm volatile("s_barrier" ::: "memory");

  bf16x8 af[2][2], bfr[2][2];

  auto ldA = [&](const short* Ab, int half) {
#pragma unroll
    for (int m = 0; m < 2; ++m) {
      const int r = wm + (half * 2 + m) * 16 + l15;
#pragma unroll
      for (int kk = 0; kk < 2; ++kk)
        af[m][kk] = *(const bf16x8*)&Ab[r * 64 + (((kk * 4 + quad) ^ xsw) << 3)];
    }
  };
  auto ldB = [&](const short* Bb) {
#pragma unroll
    for (int n = 0; n < 2; ++n) {
      const int r = wn + n * 16 + l15;
#pragma unroll
      for (int kk = 0; kk < 2; ++kk)
        bfr[n][kk] = *(const bf16x8*)&Bb[r * 64 + (((kk * 4 + quad) ^ xsw) << 3)];
    }
  };
  auto mma = [&](int half) {
    __builtin_amdgcn_s_setprio(1);
#pragma unroll
    for (int m = 0; m < 2; ++m)
#pragma unroll
      for (int n = 0; n < 2; ++n)
#pragma unroll
        for (int kk = 0; kk < 2; ++kk)
          acc[half * 2 + m][n] = MFMA16(af[m][kk], bfr[n][kk], acc[half * 2 + m][n]);
    __builtin_amdgcn_s_setprio(0);
  };

  for (int t = 0; t < NT; ++t) {
    const int cur = t & 1;
    const short* Ab = &As[cur][0];
    const short* Bb = &Bs[cur][0];

    if (t + 1 < NT) stage(cur ^ 1, t + 1);
    ldB(Bb); ldA(Ab, 0); mma(0);
    asm volatile("s_barrier" ::: "memory");
    ldA(Ab, 1); mma(1);
    asm volatile("s_waitcnt vmcnt(0)" ::: "memory");
    asm volatile("s_waitcnt lgkmcnt(0)" ::: "memory");
    asm volatile("s_barrier" ::: "memory");
  }

#pragma unroll
  for (int i = 0; i < 4; ++i)
#pragma unroll
    for (int j = 0; j < 2; ++j)
#pragma unroll
      for (int r = 0; r < 4; ++r) {
        long row = tileM + wm + i * 16 + quad * 4 + r;
        long col = tileN + wn + j * 16 + l15;
        Cf[row * N + col] = acc[i][j][r];
      }
}

// ---------------- fused RoPE (Q,K in-place in Ccat) + V transpose ---------------
// Q = Ccat cols 0..2047, K = cols 2048..2559, V = cols 2560..3071 (stride 3072).
// Vectorized x8; math identical to previous (bit-identical output).
// Q scaled by (1/8)*log2(e); V^T written slot-permuted for the attn PV A-frag.
#define ROPE_BLOCKS 2560          // Q: 2048 blocks, K: 512 blocks (x8 vectorized)
__global__ void rope_vtrans_kernel(short* __restrict__ Ccat, short* __restrict__ Vt) {
  __shared__ short tile[64][65];
  if (blockIdx.x < ROPE_BLOCKS) {
    const int QT = (B_ * S_) * NH_ * 4;  // 524288 Q threads (4 groups of 8 per head)
    int t = blockIdx.x * blockDim.x + threadIdx.x;
    long base; int g; float scale; int row;
    if (t < QT) {
      row = t >> 7; int rem = t & 127, head = rem >> 2; g = rem & 3;
      base = (long)row * CSTR + head * HD_;
      scale = 0.125f * 1.44269504f;
    } else {
      int t2 = t - QT;
      row = t2 >> 5; int rem = t2 & 31, head = rem >> 2; g = rem & 3;
      base = (long)row * CSTR + 2048 + head * HD_;
      scale = 1.0f;
    }
    const int s = row & (S_ - 1);
    const int i0 = g * 8;
    union V8 { bf16x8 v; short e[8]; };
    V8 x0, x1, y0, y1;
    x0.v = *(const bf16x8*)&Ccat[base + i0];
    x1.v = *(const bf16x8*)&Ccat[base + i0 + 32];
#pragma unroll
    for (int j = 0; j < 8; ++j) {
      const int i = i0 + j;
      float invr = exp2f((float)i * -0.41524101f) * 0.15915494309f;
      float rev = (float)s * invr;
      rev -= floorf(rev);
      float ar = rev * 6.28318530718f;
      float c = __cosf(ar), sn = __sinf(ar);
      float a = bf2f(x0.e[j]);
      float b = bf2f(x1.e[j]);
      y0.e[j] = f2bf((a * c - b * sn) * scale);
      y1.e[j] = f2bf((b * c + a * sn) * scale);
    }
    *(bf16x8*)&Ccat[base + i0]      = y0.v;
    *(bf16x8*)&Ccat[base + i0 + 32] = y1.v;
  } else {
    int blk = blockIdx.x - ROPE_BLOCKS;
    int s0 = (blk & 31) * 64;
    int h  = (blk >> 5) & 7;
    int b  = blk >> 8;
    int tid = threadIdx.x;
#pragma unroll
    for (int it = 0; it < 16; ++it) {
      int idx = tid + it * 256;
      int r = idx >> 6, c = idx & 63;
      tile[r][c] = Ccat[((long)(b * S_ + s0 + r)) * CSTR + 2560 + h * HD_ + c];
    }
    __syncthreads();
#pragma unroll
    for (int it = 0; it < 16; ++it) {
      int idx = tid + it * 256;
      int d = idx >> 6, s = idx & 63;
      int slot = (s & 0x20) | (((s >> 2) & 3) << 3) | (((s >> 4) & 1) << 2) | (s & 3);
      Vt[((long)((b * NKV_ + h) * HD_ + d)) * S_ + s0 + slot] = tile[s][d];
    }
  }
}

// ---------------- Flash attention (causal, GQA), transposed-score form ----------
// Single launch, grid (16, 64) = 1024 blocks. XCD-AWARE REMAP (T1): the linear
// block id is reinterpreted so all 64 blocks sharing one (b,hkv) K/V column
// (4 heads x 16 q-tiles) get ids == same residue mod 8 -> same XCD under the
// empirical round-robin dispatch. Each XCD then serves exactly 2 K/V columns
// = 1 MiB, fully L2-resident with 64x reuse (was: every XCD touched all 16
// columns = 8 MiB > 4 MiB L2 -> ~10 MB HBM re-fetch + ~900cy staging latency
// on the critical path). Remap is bijective; per-block work and numerics are
// identical (if the dispatch mapping differs, effect is perf-only).
// Within each XCD, qt steps fastest with qt=15 first -> LPT preserved.
// 128 q-rows per block (two 16-row fragments per wave).
// 3-buffer, 2-deep prefetch with counted vmcnt(4); one barrier per iteration.
__global__ __launch_bounds__(256, 3) void attn_kernel(
    const short* __restrict__ Ccat, const short* __restrict__ Vt,
    short* __restrict__ O)
{
  // ---- XCD-aware index derivation (pure remap of the linear block id) ----
  const int l    = (int)blockIdx.x + 16 * (int)blockIdx.y;  // 0..1023
  const int r8   = l & 7;                 // XCD residue (round-robin)
  const int m    = l >> 3;                // 0..127
  const int kvcol = r8 + 8 * (m >> 6);    // 0..15 = b*8 + hkv (2 per XCD)
  const int idx  = m & 63;                // 0..63 within column
  const int qt   = 15 - (idx & 15);       // long q-tiles dispatch first
  const int kmax = 2 * qt + 1;            // last 64-key tile index
  const int b    = kvcol >> 3;
  const int hkv  = kvcol & 7;
  const int h    = hkv * 4 + (idx >> 4);  // head within the GQA group

  const int tid = threadIdx.x, lane = tid & 63, w = tid >> 6;
  const int quad = lane >> 4, l15 = lane & 15;

  __shared__ __align__(16) short Ks[3][64 * 64];   // [key][feature], chunk-swizzled
  __shared__ __align__(16) short Vs[3][64 * 64];   // [d][slot], chunk-swizzled

  const int qbase = qt * 128 + w * 16;   // frag0 rows qbase+l15, frag1 +64
  const short* qb0 = Ccat + ((long)(b * S_ + qbase + l15)) * CSTR + h * HD_;
  const short* qb1 = qb0 + 64L * CSTR;
  const bf16x8 aq00 = *(const bf16x8*)(qb0 + quad * 8);
  const bf16x8 aq01 = *(const bf16x8*)(qb0 + 32 + quad * 8);
  const bf16x8 aq10 = *(const bf16x8*)(qb1 + quad * 8);
  const bf16x8 aq11 = *(const bf16x8*)(qb1 + 32 + quad * 8);

  f32x4 o0[4], o1[4];
#pragma unroll
  for (int i = 0; i < 4; ++i) {
    o0[i] = f32x4{0.f, 0.f, 0.f, 0.f};
    o1[i] = f32x4{0.f, 0.f, 0.f, 0.f};
  }
  f32x4 li0 = f32x4{0.f, 0.f, 0.f, 0.f};
  f32x4 li1 = f32x4{0.f, 0.f, 0.f, 0.f};

  const short* kg = Ccat + ((long)(b * S_)) * CSTR + 2048 + hkv * HD_;
  const short* vg = Vt + ((long)((b * NKV_ + hkv) * HD_)) * S_;

  const int rK = tid >> 3;                       // 0..31 (second half adds 32)
  const int cC = (tid & 7) ^ (rK & 7);           // +32 preserves &7
  const short* kSrc = kg + (long)rK * CSTR + cC * 8;
  const short* vSrc = vg + (long)rK * S_ + cC * 8;
  short* kDst = &Ks[0][tid * 8];
  short* vDst = &Vs[0][tid * 8];

  auto stage = [&](int buf, int kb) {
    const long ko = (long)kb * 64 * CSTR;
    const long vo = (long)kb * 64;
    const int bo = buf * 4096;
    gload_lds16(kSrc + ko,              kDst + bo);
    gload_lds16(kSrc + ko + 32L * CSTR, kDst + bo + 2048);
    gload_lds16(vSrc + vo,              vDst + bo);
    gload_lds16(vSrc + vo + 32L * S_,   vDst + bo + 2048);
  };

  stage(0, 0);
  if (kmax >= 1) stage(1, 1);

  const int thr = w * 16 + l15;   // diagonal mask threshold (key offset vs row)
  union U8 { uint32_t u[4]; bf16x8 v; };

  int cur = 0;
  for (int kb = 0; kb <= kmax; ++kb) {
    if (kb < kmax) asm volatile("s_waitcnt vmcnt(4)" ::: "memory");
    else           asm volatile("s_waitcnt vmcnt(0)" ::: "memory");
    asm volatile("s_barrier" ::: "memory");      // buf[cur] staged, prev reads done
    if (kb + 2 <= kmax) {
      int nb = cur + 2; if (nb >= 3) nb -= 3;
      stage(nb, kb + 2);                         // 2-deep prefetch
    }
    const short* Kb = &Ks[cur][0];
    const short* Vb = &Vs[cur][0];
    const bool doF0 = (kb != kmax);              // frag0 fully masked at kmax

    // ---- Sc^T = K·Q^T (K-frags shared across both q-fragments) ----
    f32x4 s0[4], s1[4];
    __builtin_amdgcn_s_setprio(1);
#pragma unroll
    for (int nt = 0; nt < 4; ++nt) {
      const int r = nt * 16 + l15;
      bf16x8 k0 = *(const bf16x8*)&Kb[(r * 8 + ((quad)     ^ (r & 7))) * 8];
      bf16x8 k1 = *(const bf16x8*)&Kb[(r * 8 + ((quad + 4) ^ (r & 7))) * 8];
      f32x4 t = f32x4{0.f, 0.f, 0.f, 0.f};
      t = MFMA16(k0, aq10, t);
      t = MFMA16(k1, aq11, t);
      s1[nt] = t;
      if (doF0) {
        f32x4 u = f32x4{0.f, 0.f, 0.f, 0.f};
        u = MFMA16(k0, aq00, u);
        u = MFMA16(k1, aq01, u);
        s0[nt] = u;
      }
    }
    __builtin_amdgcn_s_setprio(0);

    // ---- causal mask (diagonal tiles only) ----
    if (kb == kmax) {            // frag1 diagonal
#pragma unroll
      for (int nt = 0; nt < 4; ++nt) {
        const int base = nt * 16 + quad * 4;
#pragma unroll
        for (int rr = 0; rr < 4; ++rr)
          if (base + rr > thr) s1[nt][rr] = -1e30f;
      }
    }
    if (doF0 && kb == kmax - 1) {   // frag0 diagonal
#pragma unroll
      for (int nt = 0; nt < 4; ++nt) {
        const int base = nt * 16 + quad * 4;
#pragma unroll
        for (int rr = 0; rr < 4; ++rr)
          if (base + rr > thr) s0[nt][rr] = -1e30f;
      }
    }

    // ---- exp2 + pack to P^T B-fragments (registers only) ----
    U8 p0[2], p1[2];
#pragma unroll
    for (int kt = 0; kt < 2; ++kt) {
      float e0 = fast_exp2(s1[2 * kt][0]),     e1 = fast_exp2(s1[2 * kt][1]);
      float e2 = fast_exp2(s1[2 * kt][2]),     e3 = fast_exp2(s1[2 * kt][3]);
      float e4 = fast_exp2(s1[2 * kt + 1][0]), e5 = fast_exp2(s1[2 * kt + 1][1]);
      float e6 = fast_exp2(s1[2 * kt + 1][2]), e7 = fast_exp2(s1[2 * kt + 1][3]);
      p1[kt].u[0] = f2bf_pk(e0, e1);
      p1[kt].u[1] = f2bf_pk(e2, e3);
      p1[kt].u[2] = f2bf_pk(e4, e5);
      p1[kt].u[3] = f2bf_pk(e6, e7);
      li1 += f32x4{e0, e1, e2, e3};
      li1 += f32x4{e4, e5, e6, e7};
    }
    if (doF0) {
#pragma unroll
      for (int kt = 0; kt < 2; ++kt) {
        float e0 = fast_exp2(s0[2 * kt][0]),     e1 = fast_exp2(s0[2 * kt][1]);
        float e2 = fast_exp2(s0[2 * kt][2]),     e3 = fast_exp2(s0[2 * kt][3]);
        float e4 = fast_exp2(s0[2 * kt + 1][0]), e5 = fast_exp2(s0[2 * kt + 1][1]);
        float e6 = fast_exp2(s0[2 * kt + 1][2]), e7 = fast_exp2(s0[2 * kt + 1][3]);
        p0[kt].u[0] = f2bf_pk(e0, e1);
        p0[kt].u[1] = f2bf_pk(e2, e3);
        p0[kt].u[2] = f2bf_pk(e4, e5);
        p0[kt].u[3] = f2bf_pk(e6, e7);
        li0 += f32x4{e0, e1, e2, e3};
        li0 += f32x4{e4, e5, e6, e7};
      }
    }

    // ---- O^T += V^T · P^T (V A-frags shared across both q-fragments) ----
    __builtin_amdgcn_s_setprio(1);
#pragma unroll
    for (int kt = 0; kt < 2; ++kt) {
      bf16x8 vf[4];
#pragma unroll
      for (int dt = 0; dt < 4; ++dt)
        vf[dt] = *(const bf16x8*)&Vb[(dt * 16 + l15) * 64 +
                                     (((kt * 4 + quad) ^ (l15 & 7)) << 3)];
#pragma unroll
      for (int dt = 0; dt < 4; ++dt)
        o1[dt] = MFMA16(vf[dt], p1[kt].v, o1[dt]);
      if (doF0) {
#pragma unroll
        for (int dt = 0; dt < 4; ++dt)
          o0[dt] = MFMA16(vf[dt], p0[kt].v, o0[dt]);
      }
    }
    __builtin_amdgcn_s_setprio(0);

    asm volatile("s_waitcnt lgkmcnt(0)" ::: "memory");   // all LDS reads serviced
    ++cur; if (cur == 3) cur = 0;
  }

  // ---- epilogue: O^T C-layout -> lane holds qrow=l15, d = dt*16+quad*4+r ----
  auto epi = [&](f32x4 (&o)[4], const f32x4& li4, int qrow0) {
    float l2 = (li4[0] + li4[1]) + (li4[2] + li4[3]);
    l2 += __shfl_xor(l2, 16, 64);
    l2 += __shfl_xor(l2, 32, 64);
    float invl = 1.0f / l2;
    long orow = (long)(b * S_ + qrow0 + l15);
#pragma unroll
    for (int dt = 0; dt < 4; ++dt) {
      uint2 st;
      st.x = f2bf_pk(o[dt][0] * invl, o[dt][1] * invl);
      st.y = f2bf_pk(o[dt][2] * invl, o[dt][3] * invl);
      *(uint2*)&O[orow * (NH_ * HD_) + h * HD_ + dt * 16 + quad * 4] = st;
    }
  };
  epi(o1, li1, qbase + 64);
  epi(o0, li0, qbase);
}

// ---------------- launch -------------------------------------------------------
extern "C" void kernel_launch(void* const* d_in, const int* in_sizes, int n_in,
                              void* d_out, int out_size, void* d_ws, size_t ws_size,
                              hipStream_t stream) {
  const float* hs = (const float*)d_in[0];
  const float* Wq = (const float*)d_in[1];
  const float* Wk = (const float*)d_in[2];
  const float* Wv = (const float*)d_in[3];
  const float* Wo = (const float*)d_in[4];
  float* out = (float*)d_out;

  char* p = (char*)d_ws;
  auto carve = [&](size_t elems) { short* r = (short*)p; p += elems * 2; return r; };
  short* Xb   = carve(8388608);    // hidden bf16 [4096,2048]
  short* Wcat = carve(6291456);    // [Wq;Wk;Wv] rows -> [3072,2048]
  short* Wob  = carve(4194304);
  short* Ccat = carve(12582912);   // QKV-cat [4096,3072]
  short* Vtt  = carve(2097152);    // V^T [B,KV,HD,S] (slot-permuted)
  short* Om   = carve(8388608);    // attn out [4096,2048]

  short* Wqb = Wcat;               // rows 0..2047
  short* Wkb = Wcat + 4194304;     // rows 2048..2559
  short* Wvb = Wcat + 5242880;     // rows 2560..3071

  Cvt5Args ca{hs, Wq, Wk, Wv, Wo, Xb, Wqb, Wkb, Wvb, Wob};
  cvt5_kernel<<<CV4 / 256, 256, 0, stream>>>(ca);

  // QKV-cat projection: 128x192 tiles, grid 16x32 = 512 blocks = 2/CU
  gemm_qkvcat<<<dim3(16, 32), 512, 0, stream>>>(Xb, Wcat, Ccat);

  rope_vtrans_kernel<<<ROPE_BLOCKS + 512, 256, 0, stream>>>(Ccat, Vtt);

  // attention: single launch, grid (16,64) = 1024 blocks, XCD-aware remap
  // inside the kernel (K/V column -> one XCD; qt LPT within each XCD)
  attn_kernel<<<dim3(16, 64, 1), 256, 0, stream>>>(Ccat, Vtt, Om);

  // Output projection: 128x128 tiles, grid 16x32 = 512 blocks = 2/CU
  gemm_out<<<dim3(16, 32), 512, 0, stream>>>(Om, Wob, out);
}